// Round 11
// baseline (764.429 us; speedup 1.0000x reference)
//
#include <hip/hip_runtime.h>
#include <hip/hip_bf16.h>

// VanillaMPNN on MI355X — round 29: 3-deep async gather pipeline (global_load_lds).
// Chain model (3 confirmations: r25 inverse-occupancy, r27 work-cut 1:1,
// r28 latency-batch): per-wave serial chain dominates; remaining big term is
// 21 tiles x ~650cy gather exposure. Registers can't hold 3 tiles; LDS can:
// per-lane global src + wave-uniform LDS dst is exactly global_load_lds's
// supported shape. Flat tile list (packed nn|remc|eoff, <=48 entries) enables
// cross-node pipelining with cheap bookkeeping (r20's failure was shfl
// bookkeeping + depth-1). Counted s_waitcnt vmcnt(6) (never 0 in loop) +
// sched_barrier(0) fences; dummy zero-row issues keep the count uniform.
// LDS 17.5KB -> 9.1 blocks/CU cap (>= achieved 8.9, no r25 repeat).

#define NE 48
#define NB_SH 8                       // 256 nodes per bucket
#define SLDS_CAP 512                  // staged edge indices per wave (16-sigma margin)
#define TLIST_CAP 64
#define PD 3                          // pipeline depth (tiles in flight)

typedef __attribute__((ext_vector_type(8))) short short8;
typedef __attribute__((ext_vector_type(4))) float floatx4;

__device__ __forceinline__ unsigned short bf16_rne(float v) {
    unsigned u = __float_as_uint(v);
    u += 0x7FFFu + ((u >> 16) & 1u);
    return (unsigned short)(u >> 16);
}

// packed hi/lo split: 8 fp32 -> 8 bf16 hi + 8 bf16 lo (RNE both)
__device__ __forceinline__ void split8p(const float* __restrict__ x, short8& hi, short8& lo) {
    union { unsigned u[4]; short8 s; } H, L;
#pragma unroll
    for (int i = 0; i < 4; ++i) {
        float a = x[2 * i], b = x[2 * i + 1];
        __hip_bfloat162 h2 = __float22bfloat162_rn(make_float2(a, b));
        unsigned h = *reinterpret_cast<unsigned*>(&h2);
        float ra = a - __uint_as_float(h << 16);
        float rb = b - __uint_as_float(h & 0xFFFF0000u);
        __hip_bfloat162 l2 = __float22bfloat162_rn(make_float2(ra, rb));
        H.u[i] = h;
        L.u[i] = *reinterpret_cast<unsigned*>(&l2);
    }
    hi = H.s; lo = L.s;
}

// plain pack: 8 fp32 -> 8 bf16 (RNE), no residual
__device__ __forceinline__ short8 cvt8(const float* __restrict__ x) {
    union { unsigned u[4]; short8 s; } H;
#pragma unroll
    for (int i = 0; i < 4; ++i) {
        __hip_bfloat162 h2 = __float22bfloat162_rn(make_float2(x[2 * i], x[2 * i + 1]));
        H.u[i] = *reinterpret_cast<unsigned*>(&h2);
    }
    return H.s;
}

// async 16B/lane global->LDS (per-lane global addr, wave-uniform LDS base)
__device__ __forceinline__ void gl_lds16(const float* g, float* l) {
    __builtin_amdgcn_global_load_lds(
        (const __attribute__((address_space(1))) void*)g,
        (__attribute__((address_space(3))) void*)l, 16, 0, 0);
}

// 3 j-tiles, 6 MFMA each: acc[t] = split3(A) @ B[t]
__device__ __forceinline__ void gemm3(const short8& ah0, const short8& al0,
                                      const short8& ah1, const short8& al1,
                                      const short8* __restrict__ hi,
                                      const short8* __restrict__ lo,
                                      int lane, floatx4* acc) {
#pragma unroll
    for (int t = 0; t < 3; ++t) {
        short8 bh0 = hi[(t * 2 + 0) * 64 + lane];
        short8 bh1 = hi[(t * 2 + 1) * 64 + lane];
        short8 bl0 = lo[(t * 2 + 0) * 64 + lane];
        short8 bl1 = lo[(t * 2 + 1) * 64 + lane];
        floatx4 c = {0.0f, 0.0f, 0.0f, 0.0f};
        c = __builtin_amdgcn_mfma_f32_16x16x32_bf16(ah0, bh0, c, 0, 0, 0);
        c = __builtin_amdgcn_mfma_f32_16x16x32_bf16(ah1, bh1, c, 0, 0, 0);
        c = __builtin_amdgcn_mfma_f32_16x16x32_bf16(al0, bh0, c, 0, 0, 0);
        c = __builtin_amdgcn_mfma_f32_16x16x32_bf16(al1, bh1, c, 0, 0, 0);
        c = __builtin_amdgcn_mfma_f32_16x16x32_bf16(ah0, bl0, c, 0, 0, 0);
        c = __builtin_amdgcn_mfma_f32_16x16x32_bf16(ah1, bl1, c, 0, 0, 0);
        acc[t] = c;
    }
}

// ---------------- embed ----------------
__global__ __launch_bounds__(256) void embed_kernel(const int* __restrict__ an,
                                                    const float* __restrict__ emb,
                                                    float* __restrict__ h, int n4) {
    int i = blockIdx.x * 256 + threadIdx.x;
    if (i >= n4) return;
    int n = i / 12, q = i - n * 12;
    ((float4*)h)[i] = ((const float4*)emb)[an[n] * 12 + q];
}

// ---------------- fold: F = msg_w2 @ upd_w1, b2u1 = msg_b2 @ upd_w1 ----------------
__global__ __launch_bounds__(256) void fold_kernel(const float* __restrict__ w2,
                                                   const float* __restrict__ u1,
                                                   const float* __restrict__ b2,
                                                   float* __restrict__ F,
                                                   float* __restrict__ b2u1) {
    int idx = blockIdx.x * 256 + threadIdx.x;
    if (idx < 6 * NE * NE) {
        int l = idx / (NE * NE);
        int r = idx - l * NE * NE;
        int k = r / NE, j = r - (r / NE) * NE;
        const float* wrow = w2 + (size_t)l * NE * NE + k * NE;
        const float* ucol = u1 + (size_t)l * NE * NE + j;
        float s = 0.0f;
#pragma unroll 8
        for (int q = 0; q < NE; ++q) s = fmaf(wrow[q], ucol[q * NE], s);
        F[idx] = s;
    } else if (idx < 6 * NE * NE + 6 * NE) {
        int r = idx - 6 * NE * NE;
        int l = r / NE, j = r - l * NE;
        const float* bv = b2 + (size_t)l * NE;
        const float* ucol = u1 + (size_t)l * NE * NE + j;
        float s = 0.0f;
#pragma unroll 8
        for (int q = 0; q < NE; ++q) s = fmaf(bv[q], ucol[q * NE], s);
        b2u1[r] = s;
    }
}

// ---------------- CSR build ----------------
__global__ __launch_bounds__(256) void hist_kernel(const int* __restrict__ dst,
                                                   int* __restrict__ cnt, int E) {
    int e = blockIdx.x * 256 + threadIdx.x;
    if (e < E) atomicAdd(&cnt[dst[e]], 1);
}

__global__ __launch_bounds__(256) void scansum_kernel(const int* __restrict__ cnt,
                                                      int* __restrict__ bsum, int N) {
    __shared__ int sw[4];
    const int tid = threadIdx.x, lane = tid & 63, wid = tid >> 6;
    int base = blockIdx.x * 1024;
    int v = 0;
#pragma unroll
    for (int k = 0; k < 4; ++k) {
        int i = base + k * 256 + tid;
        v += (i < N) ? cnt[i] : 0;
    }
#pragma unroll
    for (int o = 1; o < 64; o <<= 1) v += __shfl_xor(v, o, 64);
    if (lane == 0) sw[wid] = v;
    __syncthreads();
    if (tid == 0) bsum[blockIdx.x] = sw[0] + sw[1] + sw[2] + sw[3];
}

__global__ __launch_bounds__(256) void scanb_kernel(int* __restrict__ bsum, int nblk) {
    __shared__ int s[256];
    int tid = threadIdx.x;
    s[tid] = (tid < nblk) ? bsum[tid] : 0;
    __syncthreads();
    if (tid == 0) {
        int run = 0;
        for (int i = 0; i < nblk; ++i) { int t = s[i]; s[i] = run; run += t; }
    }
    __syncthreads();
    if (tid < nblk) bsum[tid] = s[tid];
}

__global__ __launch_bounds__(1024) void scanfix_kernel(const int* __restrict__ cnt,
                                                       const int* __restrict__ bsum,
                                                       int* __restrict__ offs,
                                                       int* __restrict__ gpos, int N) {
    __shared__ int swave[16];
    const int tid = threadIdx.x, lane = tid & 63, wid = tid >> 6;
    int i = blockIdx.x * 1024 + tid;
    int orig = (i < N) ? cnt[i] : 0;
    int v = orig;
#pragma unroll
    for (int off = 1; off < 64; off <<= 1) {
        int u = __shfl_up(v, off, 64);
        if (lane >= off) v += u;
    }
    if (lane == 63) swave[wid] = v;
    __syncthreads();
    if (wid == 0) {
        int w = (lane < 16) ? swave[lane] : 0;
#pragma unroll
        for (int off = 1; off < 16; off <<= 1) {
            int u = __shfl_up(w, off, 64);
            if (lane >= off) w += u;
        }
        if (lane < 16) swave[lane] = w;
    }
    __syncthreads();
    int prefix = (wid > 0) ? swave[wid - 1] : 0;
    int val = bsum[blockIdx.x] + prefix + v - orig;
    if (i < N) {
        offs[i] = val;
        if ((i & 255) == 0) gpos[i >> 8] = val;
    }
}

__global__ __launch_bounds__(256) void partA_kernel(const int* __restrict__ src,
                                                    const int* __restrict__ dst,
                                                    int* __restrict__ gpos,
                                                    int2* __restrict__ pairbuf,
                                                    int E, int NB) {
    __shared__ int lhist[512];
    __shared__ int lbase[512];
    const int tid = threadIdx.x;
    for (int i = tid; i < NB; i += 256) lhist[i] = 0;
    __syncthreads();
    const int base = blockIdx.x * 2048;
    int ssrc[8], sdst[8], rnk[8];
#pragma unroll
    for (int k = 0; k < 8; ++k) {
        int e = base + k * 256 + tid;
        if (e < E) {
            ssrc[k] = src[e]; sdst[k] = dst[e];
            rnk[k] = atomicAdd(&lhist[sdst[k] >> NB_SH], 1);
        }
    }
    __syncthreads();
    for (int i = tid; i < NB; i += 256) {
        int c = lhist[i];
        lbase[i] = c ? atomicAdd(&gpos[i], c) : 0;
    }
    __syncthreads();
#pragma unroll
    for (int k = 0; k < 8; ++k) {
        int e = base + k * 256 + tid;
        if (e < E)
            pairbuf[lbase[sdst[k] >> NB_SH] + rnk[k]] = make_int2(ssrc[k], sdst[k]);
    }
}

__global__ __launch_bounds__(256) void partB_kernel(const int2* __restrict__ pairbuf,
                                                    int* __restrict__ offs,   // becomes END offsets
                                                    int* __restrict__ colsrc, int E) {
    int e = blockIdx.x * 256 + threadIdx.x;
    if (e < E) {
        int2 p = pairbuf[e];
        int pos = atomicAdd(&offs[p.y], 1);
        colsrc[pos] = p.x;
    }
}

// ---------------- pack 4 weight families -> B-fragment tables ----------------
__global__ __launch_bounds__(256) void pack_all_kernel(const float* __restrict__ w0,
                                                       const float* __restrict__ w1m,
                                                       const float* __restrict__ w2m,
                                                       const float* __restrict__ w3m,
                                                       short8* __restrict__ hi,
                                                       short8* __restrict__ lo) {
    int idx = blockIdx.x * 256 + threadIdx.x;
    if (idx >= 3 * 2304 + 384) return;
    int slot = idx / 2304;
    int rem  = idx - slot * 2304;
    const float* w = (slot == 0) ? w0 : (slot == 1) ? w1m : (slot == 2) ? w2m : w3m;
    int lane = rem & 63;
    int s = (rem >> 6) & 1;
    int t = (rem >> 7) % 3;
    int l = (rem >> 7) / 3;
    short8 h8, l8;
#pragma unroll
    for (int i = 0; i < 8; ++i) {
        int k = s * 32 + (lane >> 4) * 8 + i;
        int j = t * 16 + (lane & 15);
        float v = (k < NE) ? w[l * NE * NE + k * NE + j] : 0.0f;
        unsigned short hh = bf16_rne(v);
        float hf = __uint_as_float((unsigned)hh << 16);
        unsigned short ll = bf16_rne(v - hf);
        h8[i] = (short)hh;
        l8[i] = (short)ll;
    }
    hi[idx] = h8;
    lo[idx] = l8;
}

// ---------------- fused layer: async-pipelined edge agg + folded node transform ----------------
__global__ __launch_bounds__(64, 4) void layer_kernel(
    const float* __restrict__ hin,
    const int* __restrict__ colsrc,
    const int* __restrict__ ends,
    const int* __restrict__ cnt,
    float* __restrict__ hout,
    const short8* __restrict__ bhi,               // msg_w1 frags [3][2][64]
    const short8* __restrict__ blo,               // (unused in edge)
    const float* __restrict__ b1,                 // msg_b1
    const short8* __restrict__ f1hi, const short8* __restrict__ f1lo,   // F = W2*U1
    const float* __restrict__ b2u1v,
    const float* __restrict__ ub1,
    const short8* __restrict__ u2hi, const short8* __restrict__ u2lo,   // upd_w2
    const float* __restrict__ ub2,
    int N,
    int final_layer,
    const int* __restrict__ gid,
    const short8* __restrict__ rw1hi, const short8* __restrict__ rw1lo,
    const float* __restrict__ rb1, const float* __restrict__ rw2,
    const float* __restrict__ rb2, float* __restrict__ out)
{
    __shared__ float mytile[16][52];              // 16x48 agg tile (+pad)
    __shared__ float hdls[16][48];                // staged dst rows
    __shared__ int   slds[SLDS_CAP];              // staged edge indices
    __shared__ int   tlist[TLIST_CAP];            // flat tile list: nn<<16|remc<<11|eoff
    __shared__ float xst[PD][768];                // pipeline slots: 16 rows x 48 floats

    const int lane = threadIdx.x;
    const int n0   = blockIdx.x * 16;
    if (n0 >= N) return;

    const int m  = lane & 15;
    const int kb = lane >> 4;

    // ---- coop-stage 16 dst rows ----
    {
        const float4* sp = (const float4*)(hin + (size_t)n0 * NE);
        float4* dp = (float4*)hdls;
#pragma unroll
        for (int f = 0; f < 3; ++f) dp[lane + f * 64] = sp[lane + f * 64];
    }

    // ---- per-node metadata (lane m holds node m's values) ----
    const int mydeg = cnt[n0 + m];
    const int myend = ends[n0 + m];

    const int beg0 = __shfl(myend - mydeg, 0, 64);
    const int endL = __shfl(myend, 15, 64);
    const int tot  = endL - beg0;
    const bool uselds = (tot <= SLDS_CAP);
    if (uselds) {
        for (int i = lane; i < tot; i += 64) slds[i] = colsrc[beg0 + i];
    }

    // ---- build flat tile list (lanes 0..15, one node each) ----
    int ttot = 0;
    if (uselds) {
        const int ntile_m = (mydeg + 15) >> 4;
        int pref = ntile_m;
#pragma unroll
        for (int o = 1; o < 16; o <<= 1) {
            int u = __shfl_up(pref, o, 64);
            if ((lane & 15) >= o) pref += u;
        }
        // lanes 16.. have junk pref; only lane<16 writes; ttot from lane 15
        ttot = __shfl(pref, 15, 64);
        if (lane < 16) {
            const int tstart = pref - ntile_m;
            const int begrel = (myend - mydeg) - beg0;
            for (int it = 0; it < ntile_m; ++it) {
                int rem = mydeg - it * 16;
                int remc = rem < 16 ? rem : 16;
                tlist[tstart + it] = (lane << 16) | (remc << 11) | (begrel + it * 16);
            }
        }
    }

    // ---- edge weight fragments (bf16 hi only) ----
    short8 bh[6];
#pragma unroll
    for (int i = 0; i < 6; ++i) bh[i] = bhi[i * 64 + lane];
    const float bb0 = b1[m], bb1 = b1[16 + m], bb2 = b1[32 + m];
    const float rbb0 = fmaxf(bb0, 0.0f), rbb1 = fmaxf(bb1, 0.0f), rbb2 = fmaxf(bb2, 0.0f);
    const float rbb_mine = (lane < 16) ? rbb0 : (lane < 32) ? rbb1 : rbb2;

    // ---- pre-zero agg rows (covers deg-0 nodes) ----
    {
        float4 z = make_float4(0, 0, 0, 0);
        float4* zp = (float4*)&mytile[lane >> 2][(lane & 3) * 12];
        zp[0] = z; zp[1] = z; zp[2] = z;
    }
    asm volatile("s_waitcnt vmcnt(0) lgkmcnt(0)" ::: "memory");  // stages + tlist visible

    // finalize helper (uniform call sites)
    float s0 = 0.0f, s1 = 0.0f, s2 = 0.0f;
    auto finalize = [&](int nn) {
        s0 += __shfl_xor(s0, 16, 64); s0 += __shfl_xor(s0, 32, 64);
        s1 += __shfl_xor(s1, 16, 64); s1 += __shfl_xor(s1, 32, 64);
        s2 += __shfl_xor(s2, 16, 64); s2 += __shfl_xor(s2, 32, 64);
        float t1v = __shfl(s1, lane & 15, 64);
        float t2v = __shfl(s2, lane & 15, 64);
        float val = (lane < 16) ? s0 : (lane < 32) ? t1v : t2v;
        int deg = __shfl(mydeg, nn, 64);
        float npad = (float)((((deg + 15) >> 4) << 4) - deg);
        val = fmaf(-npad, rbb_mine, val);
        if (lane < 48) mytile[nn][lane] = val;
    };

    if (uselds) {
        // -------- 3-deep async pipeline over flat tile stream --------
        const int r_iss = lane & 15, cg_iss = lane >> 4;
        auto issue_tile = [&](int ent, int slot, bool dummy) {
            int srow;
            if (dummy) {
                srow = N;
            } else {
                int eoff = ent & 2047;
                int remc = (ent >> 11) & 31;
                int sr = slds[eoff + r_iss];
                srow = (r_iss < remc) ? sr : N;
            }
            const float* gp = hin + (size_t)srow * NE + cg_iss * 4;
            float* lb = &xst[slot][0];
            gl_lds16(gp,      lb);        // floats [0,16) of each row
            gl_lds16(gp + 16, lb + 256);  // floats [16,32)
            gl_lds16(gp + 32, lb + 512);  // floats [32,48)
        };

        if (ttot > 0) {
            // prologue: fill PD slots (dummies if short)
#pragma unroll
            for (int i = 0; i < PD; ++i) {
                bool real = i < ttot;
                issue_tile(real ? tlist[i] : 0, i, !real);
            }

            int curn = -1;
            float4 d0a = make_float4(0,0,0,0), d0b = d0a, d1a = d0a, d1b = d0a;
            int slot = 0;
#pragma unroll 1
            for (int t = 0; t < ttot; ++t) {
                int ent = tlist[t];
                int nn = ent >> 16;
                if (nn != curn) {
                    if (curn >= 0) finalize(curn);
                    curn = nn; s0 = s1 = s2 = 0.0f;
                    const float* hr = hdls[nn];
                    d0a = *(const float4*)(hr + kb * 8);
                    d0b = *(const float4*)(hr + kb * 8 + 4);
                    if (kb < 2) {
                        d1a = *(const float4*)(hr + 32 + kb * 8);
                        d1b = *(const float4*)(hr + 32 + kb * 8 + 4);
                    }
                }

                asm volatile("s_waitcnt vmcnt(6)" ::: "memory");   // 3*(PD-1): tile t landed
                __builtin_amdgcn_sched_barrier(0);

                // read tile from slot: row m, float4 at chunk ch -> off = (ch>>2)*256+(ch&3)*64+m*4
                const float* xb = &xst[slot][0];
                const int o0 = (kb >> 1) * 256 + (kb & 1) * 128 + m * 4;  // chunk 2kb
                float4 a0 = *(const float4*)(xb + o0);
                float4 a1 = *(const float4*)(xb + o0 + 64);               // chunk 2kb+1
                float x0[8], x1[8];
                x0[0] = a0.x * d0a.x; x0[1] = a0.y * d0a.y; x0[2] = a0.z * d0a.z; x0[3] = a0.w * d0a.w;
                x0[4] = a1.x * d0b.x; x0[5] = a1.y * d0b.y; x0[6] = a1.z * d0b.z; x0[7] = a1.w * d0b.w;
                if (kb < 2) {
                    const int o2 = 512 + kb * 128 + m * 4;                // chunk 8+2kb
                    float4 a2 = *(const float4*)(xb + o2);
                    float4 a3 = *(const float4*)(xb + o2 + 64);
                    x1[0] = a2.x * d1a.x; x1[1] = a2.y * d1a.y; x1[2] = a2.z * d1a.z; x1[3] = a2.w * d1a.w;
                    x1[4] = a3.x * d1b.x; x1[5] = a3.y * d1b.y; x1[6] = a3.z * d1b.z; x1[7] = a3.w * d1b.w;
                } else {
#pragma unroll
                    for (int i = 0; i < 8; ++i) x1[i] = 0.0f;
                }

                short8 ah0 = cvt8(x0);
                short8 ah1 = cvt8(x1);
#pragma unroll
                for (int tt = 0; tt < 3; ++tt) {
                    floatx4 cc = {0.0f, 0.0f, 0.0f, 0.0f};
                    cc = __builtin_amdgcn_mfma_f32_16x16x32_bf16(ah0, bh[tt * 2 + 0], cc, 0, 0, 0);
                    cc = __builtin_amdgcn_mfma_f32_16x16x32_bf16(ah1, bh[tt * 2 + 1], cc, 0, 0, 0);
                    const float bb = (tt == 0) ? bb0 : (tt == 1) ? bb1 : bb2;
                    float ts = 0.0f;
#pragma unroll
                    for (int r = 0; r < 4; ++r)
                        ts += fmaxf(cc[r] + bb, 0.0f);
                    if (tt == 0) s0 += ts; else if (tt == 1) s1 += ts; else s2 += ts;
                }

                __builtin_amdgcn_sched_barrier(0);
                // refill this slot with tile t+PD (or dummy) to keep vmcnt uniform
                int t2 = t + PD;
                bool real = t2 < ttot;
                issue_tile(real ? tlist[t2] : 0, slot, !real);
                slot = (slot == PD - 1) ? 0 : slot + 1;
            }
            if (curn >= 0) finalize(curn);
            asm volatile("s_waitcnt vmcnt(0)" ::: "memory");  // drain dummies
        }
    } else {
        // -------- fallback: direct (r28-style) path, no staged indices --------
#pragma unroll 1
        for (int nn = 0; nn < 16; ++nn) {
            const int deg = __shfl(mydeg, nn, 64);
            const int end = __shfl(myend, nn, 64);
            const int beg = end - deg;
            const float* hr = hdls[nn];
            float4 d0a = *(const float4*)(hr + kb * 8);
            float4 d0b = *(const float4*)(hr + kb * 8 + 4);
            float4 d1a = make_float4(0, 0, 0, 0), d1b = d1a;
            if (kb < 2) {
                d1a = *(const float4*)(hr + 32 + kb * 8);
                d1b = *(const float4*)(hr + 32 + kb * 8 + 4);
            }
            s0 = s1 = s2 = 0.0f;
            const int ntile = (deg + 15) >> 4;
            for (int it = 0; it < ntile; ++it) {
                const int rem = deg - it * 16;
                int srow = (m < rem) ? colsrc[beg + it * 16 + m] : N;
                const float* hs = hin + (size_t)srow * NE + kb * 8;
                float x0[8], x1[8];
                {
                    float4 a0 = ((const float4*)hs)[0];
                    float4 a1 = ((const float4*)hs)[1];
                    x0[0] = a0.x * d0a.x; x0[1] = a0.y * d0a.y; x0[2] = a0.z * d0a.z; x0[3] = a0.w * d0a.w;
                    x0[4] = a1.x * d0b.x; x0[5] = a1.y * d0b.y; x0[6] = a1.z * d0b.z; x0[7] = a1.w * d0b.w;
                }
                if (kb < 2) {
                    float4 a0 = ((const float4*)(hs + 32))[0];
                    float4 a1 = ((const float4*)(hs + 32))[1];
                    x1[0] = a0.x * d1a.x; x1[1] = a0.y * d1a.y; x1[2] = a0.z * d1a.z; x1[3] = a0.w * d1a.w;
                    x1[4] = a1.x * d1b.x; x1[5] = a1.y * d1b.y; x1[6] = a1.z * d1b.z; x1[7] = a1.w * d1b.w;
                } else {
#pragma unroll
                    for (int i = 0; i < 8; ++i) x1[i] = 0.0f;
                }
                short8 ah0 = cvt8(x0);
                short8 ah1 = cvt8(x1);
#pragma unroll
                for (int tt = 0; tt < 3; ++tt) {
                    floatx4 cc = {0.0f, 0.0f, 0.0f, 0.0f};
                    cc = __builtin_amdgcn_mfma_f32_16x16x32_bf16(ah0, bh[tt * 2 + 0], cc, 0, 0, 0);
                    cc = __builtin_amdgcn_mfma_f32_16x16x32_bf16(ah1, bh[tt * 2 + 1], cc, 0, 0, 0);
                    const float bb = (tt == 0) ? bb0 : (tt == 1) ? bb1 : bb2;
                    float ts = 0.0f;
#pragma unroll
                    for (int r = 0; r < 4; ++r)
                        ts += fmaxf(cc[r] + bb, 0.0f);
                    if (tt == 0) s0 += ts; else if (tt == 1) s1 += ts; else s2 += ts;
                }
            }
            finalize(nn);
        }
    }
    asm volatile("s_waitcnt lgkmcnt(0)" ::: "memory");

    // ---------------- node phase: 2 GEMMs (folded, full hi/lo) + fused readout ----------------
    float c0[8], c1[8];
    {
        const float* row = &mytile[m][0];
        *(float4*)(c0)     = *(const float4*)(row + kb * 8);
        *(float4*)(c0 + 4) = *(const float4*)(row + kb * 8 + 4);
        if (kb < 2) {
            *(float4*)(c1)     = *(const float4*)(row + 32 + kb * 8);
            *(float4*)(c1 + 4) = *(const float4*)(row + 32 + kb * 8 + 4);
        } else {
#pragma unroll
            for (int i = 0; i < 8; ++i) c1[i] = 0.0f;
        }
    }
    asm volatile("s_waitcnt lgkmcnt(0)" ::: "memory");
    short8 ah0, al0, ah1, al1;
    split8p(c0, ah0, al0);
    split8p(c1, ah1, al1);

    floatx4 acc[3];
    gemm3(ah0, al0, ah1, al1, f1hi, f1lo, lane, acc);   // agg @ F
    {
        float dj[3], bj[3];
#pragma unroll
        for (int t = 0; t < 3; ++t) { dj[t] = b2u1v[t * 16 + m]; bj[t] = ub1[t * 16 + m]; }
#pragma unroll
        for (int r = 0; r < 4; ++r) {
            float fd = (float)__shfl(mydeg, kb * 4 + r, 64);
#pragma unroll
            for (int t = 0; t < 3; ++t)
                acc[t][r] = fmaxf(fmaf(fd, dj[t], acc[t][r]) + bj[t], 0.0f);
        }
    }

    // transpose C->A, GEMM2: T @ U2
#pragma unroll
    for (int t = 0; t < 3; ++t)
#pragma unroll
        for (int r = 0; r < 4; ++r)
            mytile[kb * 4 + r][t * 16 + m] = acc[t][r];
    asm volatile("s_waitcnt lgkmcnt(0)" ::: "memory");
    {
        const float* row = &mytile[m][0];
        *(float4*)(c0)     = *(const float4*)(row + kb * 8);
        *(float4*)(c0 + 4) = *(const float4*)(row + kb * 8 + 4);
        if (kb < 2) {
            *(float4*)(c1)     = *(const float4*)(row + 32 + kb * 8);
            *(float4*)(c1 + 4) = *(const float4*)(row + 32 + kb * 8 + 4);
        } else {
#pragma unroll
            for (int i = 0; i < 8; ++i) c1[i] = 0.0f;
        }
    }
    asm volatile("s_waitcnt lgkmcnt(0)" ::: "memory");
    split8p(c0, ah0, al0);
    split8p(c1, ah1, al1);
    gemm3(ah0, al0, ah1, al1, u2hi, u2lo, lane, acc);

    // out_h = hin + ub2 + acc  (residual from staged hdls)
    {
        float bj[3];
#pragma unroll
        for (int t = 0; t < 3; ++t) bj[t] = ub2[t * 16 + m];
#pragma unroll
        for (int r = 0; r < 4; ++r) {
#pragma unroll
            for (int t = 0; t < 3; ++t)
                acc[t][r] += hdls[kb * 4 + r][t * 16 + m] + bj[t];
        }
    }

    if (!final_layer) {
#pragma unroll
        for (int r = 0; r < 4; ++r) {
            const size_t row = (size_t)(n0 + kb * 4 + r) * NE;
#pragma unroll
            for (int t = 0; t < 3; ++t)
                hout[row + t * 16 + m] = acc[t][r];
        }
        return;
    }

    // fused readout
#pragma unroll
    for (int t = 0; t < 3; ++t)
#pragma unroll
        for (int r = 0; r < 4; ++r)
            mytile[kb * 4 + r][t * 16 + m] = acc[t][r];
    asm volatile("s_waitcnt lgkmcnt(0)" ::: "memory");
    {
        const float* row = &mytile[m][0];
        *(float4*)(c0)     = *(const float4*)(row + kb * 8);
        *(float4*)(c0 + 4) = *(const float4*)(row + kb * 8 + 4);
        if (kb < 2) {
            *(float4*)(c1)     = *(const float4*)(row + 32 + kb * 8);
            *(float4*)(c1 + 4) = *(const float4*)(row + 32 + kb * 8 + 4);
        } else {
#pragma unroll
            for (int i = 0; i < 8; ++i) c1[i] = 0.0f;
        }
    }
    split8p(c0, ah0, al0);
    split8p(c1, ah1, al1);
    gemm3(ah0, al0, ah1, al1, rw1hi, rw1lo, lane, acc);

    float p[4] = {0.0f, 0.0f, 0.0f, 0.0f};
    {
        float bj[3], wj[3];
#pragma unroll
        for (int t = 0; t < 3; ++t) { bj[t] = rb1[t * 16 + m]; wj[t] = rw2[t * 16 + m]; }
#pragma unroll
        for (int t = 0; t < 3; ++t)
#pragma unroll
            for (int r = 0; r < 4; ++r)
                p[r] = fmaf(fmaxf(acc[t][r] + bj[t], 0.0f), wj[t], p[r]);
    }
#pragma unroll
    for (int o = 1; o < 16; o <<= 1) {
#pragma unroll
        for (int r = 0; r < 4; ++r) p[r] += __shfl_xor(p[r], o, 16);
    }
    if (m == 0) {
        float b2v = rb2[0];
#pragma unroll
        for (int r = 0; r < 4; ++r) {
            int n = n0 + kb * 4 + r;
            atomicAdd(out + gid[n], p[r] + b2v);
        }
    }
}

extern "C" void kernel_launch(void* const* d_in, const int* in_sizes, int n_in,
                              void* d_out, int out_size, void* d_ws, size_t ws_size,
                              hipStream_t stream) {
    const int*   AtomicNum = (const int*)  d_in[0];
    const int*   Edge      = (const int*)  d_in[1];
    const int*   graph_id  = (const int*)  d_in[2];
    const float* emb       = (const float*)d_in[3];
    const float* msg_w1    = (const float*)d_in[4];
    const float* msg_b1    = (const float*)d_in[5];
    const float* msg_w2    = (const float*)d_in[6];
    const float* msg_b2    = (const float*)d_in[7];
    const float* upd_w1    = (const float*)d_in[8];
    const float* upd_b1    = (const float*)d_in[9];
    const float* upd_w2    = (const float*)d_in[10];
    const float* upd_b2    = (const float*)d_in[11];
    const float* ro_w1     = (const float*)d_in[12];
    const float* ro_b1     = (const float*)d_in[13];
    const float* ro_w2     = (const float*)d_in[14];
    const float* ro_b2     = (const float*)d_in[15];

    const int N = in_sizes[0];          // 100000 (divisible by 16)
    const int E = in_sizes[1] / 2;      // 1600000
    const int* src = Edge;
    const int* dst = Edge + E;
    const int NB = (N + 255) >> NB_SH;  // 391 dst-buckets
    const int NBLK = (N + 1023) / 1024; // 98 scan blocks

    // workspace layout (~46 MB); h/h2 have N+1 rows (row N = zero pad row).
    float*  h    = (float*)d_ws;                       // (N+1)*48
    float*  h2   = h  + (size_t)(N + 1) * NE;          // (N+1)*48
    int*    cnt  = (int*)(h2 + (size_t)(N + 1) * NE);  // N
    int*    offs = cnt + N;                            // N (end offsets after partB)
    int*    colsrc = offs + N;                         // E
    short8* whi  = (short8*)(colsrc + E);              // 3*2304 + 384
    short8* wlo  = whi + (3 * 2304 + 384);
    int*    gpos = (int*)(wlo + (3 * 2304 + 384));     // NB
    int*    bsum = gpos + NB;                          // NBLK
    float*  foldF = (float*)(bsum + NBLK);             // 6*48*48
    float*  b2u1  = foldF + 6 * NE * NE;               // 6*48
    int2*   pairbuf = (int2*)h2;                       // E (aliases h2)

    hipMemsetAsync(d_out, 0, (size_t)out_size * sizeof(float), stream);
    hipMemsetAsync(cnt, 0, (size_t)N * sizeof(int), stream);
    hipMemsetAsync(h  + (size_t)N * NE, 0, NE * sizeof(float), stream);  // zero pad row
    hipMemsetAsync(h2 + (size_t)N * NE, 0, NE * sizeof(float), stream);  // zero pad row

    int n4 = N * 12;
    embed_kernel<<<(n4 + 255) / 256, 256, 0, stream>>>(AtomicNum, emb, h, n4);

    fold_kernel<<<(6 * NE * NE + 6 * NE + 255) / 256, 256, 0, stream>>>(
        msg_w2, upd_w1, msg_b2, foldF, b2u1);

    hist_kernel<<<(E + 255) / 256, 256, 0, stream>>>(dst, cnt, E);
    scansum_kernel<<<NBLK, 256, 0, stream>>>(cnt, bsum, N);
    scanb_kernel<<<1, 256, 0, stream>>>(bsum, NBLK);
    scanfix_kernel<<<NBLK, 1024, 0, stream>>>(cnt, bsum, offs, gpos, N);
    partA_kernel<<<(E + 2047) / 2048, 256, 0, stream>>>(src, dst, gpos, pairbuf, E, NB);
    partB_kernel<<<(E + 255) / 256, 256, 0, stream>>>(pairbuf, offs, colsrc, E);

    pack_all_kernel<<<(3 * 2304 + 384 + 255) / 256, 256, 0, stream>>>(
        msg_w1, foldF, upd_w2, ro_w1, whi, wlo);

    const float* hin = h;
    float* hout = h2;
    for (int l = 0; l < 6; ++l) {
        layer_kernel<<<N / 16, 64, 0, stream>>>(
            hin, colsrc, offs, cnt, hout,
            whi + 0 * 2304 + (size_t)l * 384, wlo + 0 * 2304 + (size_t)l * 384,
            msg_b1 + (size_t)l * NE,
            whi + 1 * 2304 + (size_t)l * 384, wlo + 1 * 2304 + (size_t)l * 384,
            b2u1 + (size_t)l * NE,
            upd_b1 + (size_t)l * NE,
            whi + 2 * 2304 + (size_t)l * 384, wlo + 2 * 2304 + (size_t)l * 384,
            upd_b2 + (size_t)l * NE,
            N,
            (l == 5) ? 1 : 0,
            graph_id,
            whi + 3 * 2304, wlo + 3 * 2304,
            ro_b1, ro_w2, ro_b2, (float*)d_out);
        const float* tmp = hin; hin = hout; hout = (float*)tmp;
    }
}

// Round 12
// 761.347 us; speedup vs baseline: 1.0040x; 1.0040x over previous
//
#include <hip/hip_runtime.h>
#include <hip/hip_bf16.h>

// VanillaMPNN on MI355X — round 30: r29 pipeline on an LDS diet.
// r29 post-mortem: async pipeline DID cut the chain (19k->16k cy, inferred
// from time*waves) but 17.5KB LDS capped residency at 9.1 blocks and achieved
// waves fell 8.9->6.3 — occupancy loss ate the win. Cross-round curve says
// natural residency ~9 waves; LDS must stay <=14KB. This round: PD=2
// (xst 6.1KB, vmcnt(3)), slds 384 (8-sigma margin, fallback kept),
// total LDS 14.0KB -> cap 11.4 blocks. Everything else = r29.

#define NE 48
#define NB_SH 8                       // 256 nodes per bucket
#define SLDS_CAP 384                  // staged edge indices per wave (8-sigma margin)
#define TLIST_CAP 64
#define PD 2                          // pipeline depth (tiles in flight)

typedef __attribute__((ext_vector_type(8))) short short8;
typedef __attribute__((ext_vector_type(4))) float floatx4;

__device__ __forceinline__ unsigned short bf16_rne(float v) {
    unsigned u = __float_as_uint(v);
    u += 0x7FFFu + ((u >> 16) & 1u);
    return (unsigned short)(u >> 16);
}

// packed hi/lo split: 8 fp32 -> 8 bf16 hi + 8 bf16 lo (RNE both)
__device__ __forceinline__ void split8p(const float* __restrict__ x, short8& hi, short8& lo) {
    union { unsigned u[4]; short8 s; } H, L;
#pragma unroll
    for (int i = 0; i < 4; ++i) {
        float a = x[2 * i], b = x[2 * i + 1];
        __hip_bfloat162 h2 = __float22bfloat162_rn(make_float2(a, b));
        unsigned h = *reinterpret_cast<unsigned*>(&h2);
        float ra = a - __uint_as_float(h << 16);
        float rb = b - __uint_as_float(h & 0xFFFF0000u);
        __hip_bfloat162 l2 = __float22bfloat162_rn(make_float2(ra, rb));
        H.u[i] = h;
        L.u[i] = *reinterpret_cast<unsigned*>(&l2);
    }
    hi = H.s; lo = L.s;
}

// plain pack: 8 fp32 -> 8 bf16 (RNE), no residual
__device__ __forceinline__ short8 cvt8(const float* __restrict__ x) {
    union { unsigned u[4]; short8 s; } H;
#pragma unroll
    for (int i = 0; i < 4; ++i) {
        __hip_bfloat162 h2 = __float22bfloat162_rn(make_float2(x[2 * i], x[2 * i + 1]));
        H.u[i] = *reinterpret_cast<unsigned*>(&h2);
    }
    return H.s;
}

// async 16B/lane global->LDS (per-lane global addr, wave-uniform LDS base)
__device__ __forceinline__ void gl_lds16(const float* g, float* l) {
    __builtin_amdgcn_global_load_lds(
        (const __attribute__((address_space(1))) void*)g,
        (__attribute__((address_space(3))) void*)l, 16, 0, 0);
}

// 3 j-tiles, 6 MFMA each: acc[t] = split3(A) @ B[t]
__device__ __forceinline__ void gemm3(const short8& ah0, const short8& al0,
                                      const short8& ah1, const short8& al1,
                                      const short8* __restrict__ hi,
                                      const short8* __restrict__ lo,
                                      int lane, floatx4* acc) {
#pragma unroll
    for (int t = 0; t < 3; ++t) {
        short8 bh0 = hi[(t * 2 + 0) * 64 + lane];
        short8 bh1 = hi[(t * 2 + 1) * 64 + lane];
        short8 bl0 = lo[(t * 2 + 0) * 64 + lane];
        short8 bl1 = lo[(t * 2 + 1) * 64 + lane];
        floatx4 c = {0.0f, 0.0f, 0.0f, 0.0f};
        c = __builtin_amdgcn_mfma_f32_16x16x32_bf16(ah0, bh0, c, 0, 0, 0);
        c = __builtin_amdgcn_mfma_f32_16x16x32_bf16(ah1, bh1, c, 0, 0, 0);
        c = __builtin_amdgcn_mfma_f32_16x16x32_bf16(al0, bh0, c, 0, 0, 0);
        c = __builtin_amdgcn_mfma_f32_16x16x32_bf16(al1, bh1, c, 0, 0, 0);
        c = __builtin_amdgcn_mfma_f32_16x16x32_bf16(ah0, bl0, c, 0, 0, 0);
        c = __builtin_amdgcn_mfma_f32_16x16x32_bf16(ah1, bl1, c, 0, 0, 0);
        acc[t] = c;
    }
}

// ---------------- embed ----------------
__global__ __launch_bounds__(256) void embed_kernel(const int* __restrict__ an,
                                                    const float* __restrict__ emb,
                                                    float* __restrict__ h, int n4) {
    int i = blockIdx.x * 256 + threadIdx.x;
    if (i >= n4) return;
    int n = i / 12, q = i - n * 12;
    ((float4*)h)[i] = ((const float4*)emb)[an[n] * 12 + q];
}

// ---------------- fold: F = msg_w2 @ upd_w1, b2u1 = msg_b2 @ upd_w1 ----------------
__global__ __launch_bounds__(256) void fold_kernel(const float* __restrict__ w2,
                                                   const float* __restrict__ u1,
                                                   const float* __restrict__ b2,
                                                   float* __restrict__ F,
                                                   float* __restrict__ b2u1) {
    int idx = blockIdx.x * 256 + threadIdx.x;
    if (idx < 6 * NE * NE) {
        int l = idx / (NE * NE);
        int r = idx - l * NE * NE;
        int k = r / NE, j = r - (r / NE) * NE;
        const float* wrow = w2 + (size_t)l * NE * NE + k * NE;
        const float* ucol = u1 + (size_t)l * NE * NE + j;
        float s = 0.0f;
#pragma unroll 8
        for (int q = 0; q < NE; ++q) s = fmaf(wrow[q], ucol[q * NE], s);
        F[idx] = s;
    } else if (idx < 6 * NE * NE + 6 * NE) {
        int r = idx - 6 * NE * NE;
        int l = r / NE, j = r - l * NE;
        const float* bv = b2 + (size_t)l * NE;
        const float* ucol = u1 + (size_t)l * NE * NE + j;
        float s = 0.0f;
#pragma unroll 8
        for (int q = 0; q < NE; ++q) s = fmaf(bv[q], ucol[q * NE], s);
        b2u1[r] = s;
    }
}

// ---------------- CSR build ----------------
__global__ __launch_bounds__(256) void hist_kernel(const int* __restrict__ dst,
                                                   int* __restrict__ cnt, int E) {
    int e = blockIdx.x * 256 + threadIdx.x;
    if (e < E) atomicAdd(&cnt[dst[e]], 1);
}

__global__ __launch_bounds__(256) void scansum_kernel(const int* __restrict__ cnt,
                                                      int* __restrict__ bsum, int N) {
    __shared__ int sw[4];
    const int tid = threadIdx.x, lane = tid & 63, wid = tid >> 6;
    int base = blockIdx.x * 1024;
    int v = 0;
#pragma unroll
    for (int k = 0; k < 4; ++k) {
        int i = base + k * 256 + tid;
        v += (i < N) ? cnt[i] : 0;
    }
#pragma unroll
    for (int o = 1; o < 64; o <<= 1) v += __shfl_xor(v, o, 64);
    if (lane == 0) sw[wid] = v;
    __syncthreads();
    if (tid == 0) bsum[blockIdx.x] = sw[0] + sw[1] + sw[2] + sw[3];
}

__global__ __launch_bounds__(256) void scanb_kernel(int* __restrict__ bsum, int nblk) {
    __shared__ int s[256];
    int tid = threadIdx.x;
    s[tid] = (tid < nblk) ? bsum[tid] : 0;
    __syncthreads();
    if (tid == 0) {
        int run = 0;
        for (int i = 0; i < nblk; ++i) { int t = s[i]; s[i] = run; run += t; }
    }
    __syncthreads();
    if (tid < nblk) bsum[tid] = s[tid];
}

__global__ __launch_bounds__(1024) void scanfix_kernel(const int* __restrict__ cnt,
                                                       const int* __restrict__ bsum,
                                                       int* __restrict__ offs,
                                                       int* __restrict__ gpos, int N) {
    __shared__ int swave[16];
    const int tid = threadIdx.x, lane = tid & 63, wid = tid >> 6;
    int i = blockIdx.x * 1024 + tid;
    int orig = (i < N) ? cnt[i] : 0;
    int v = orig;
#pragma unroll
    for (int off = 1; off < 64; off <<= 1) {
        int u = __shfl_up(v, off, 64);
        if (lane >= off) v += u;
    }
    if (lane == 63) swave[wid] = v;
    __syncthreads();
    if (wid == 0) {
        int w = (lane < 16) ? swave[lane] : 0;
#pragma unroll
        for (int off = 1; off < 16; off <<= 1) {
            int u = __shfl_up(w, off, 64);
            if (lane >= off) w += u;
        }
        if (lane < 16) swave[lane] = w;
    }
    __syncthreads();
    int prefix = (wid > 0) ? swave[wid - 1] : 0;
    int val = bsum[blockIdx.x] + prefix + v - orig;
    if (i < N) {
        offs[i] = val;
        if ((i & 255) == 0) gpos[i >> 8] = val;
    }
}

__global__ __launch_bounds__(256) void partA_kernel(const int* __restrict__ src,
                                                    const int* __restrict__ dst,
                                                    int* __restrict__ gpos,
                                                    int2* __restrict__ pairbuf,
                                                    int E, int NB) {
    __shared__ int lhist[512];
    __shared__ int lbase[512];
    const int tid = threadIdx.x;
    for (int i = tid; i < NB; i += 256) lhist[i] = 0;
    __syncthreads();
    const int base = blockIdx.x * 2048;
    int ssrc[8], sdst[8], rnk[8];
#pragma unroll
    for (int k = 0; k < 8; ++k) {
        int e = base + k * 256 + tid;
        if (e < E) {
            ssrc[k] = src[e]; sdst[k] = dst[e];
            rnk[k] = atomicAdd(&lhist[sdst[k] >> NB_SH], 1);
        }
    }
    __syncthreads();
    for (int i = tid; i < NB; i += 256) {
        int c = lhist[i];
        lbase[i] = c ? atomicAdd(&gpos[i], c) : 0;
    }
    __syncthreads();
#pragma unroll
    for (int k = 0; k < 8; ++k) {
        int e = base + k * 256 + tid;
        if (e < E)
            pairbuf[lbase[sdst[k] >> NB_SH] + rnk[k]] = make_int2(ssrc[k], sdst[k]);
    }
}

__global__ __launch_bounds__(256) void partB_kernel(const int2* __restrict__ pairbuf,
                                                    int* __restrict__ offs,   // becomes END offsets
                                                    int* __restrict__ colsrc, int E) {
    int e = blockIdx.x * 256 + threadIdx.x;
    if (e < E) {
        int2 p = pairbuf[e];
        int pos = atomicAdd(&offs[p.y], 1);
        colsrc[pos] = p.x;
    }
}

// ---------------- pack 4 weight families -> B-fragment tables ----------------
__global__ __launch_bounds__(256) void pack_all_kernel(const float* __restrict__ w0,
                                                       const float* __restrict__ w1m,
                                                       const float* __restrict__ w2m,
                                                       const float* __restrict__ w3m,
                                                       short8* __restrict__ hi,
                                                       short8* __restrict__ lo) {
    int idx = blockIdx.x * 256 + threadIdx.x;
    if (idx >= 3 * 2304 + 384) return;
    int slot = idx / 2304;
    int rem  = idx - slot * 2304;
    const float* w = (slot == 0) ? w0 : (slot == 1) ? w1m : (slot == 2) ? w2m : w3m;
    int lane = rem & 63;
    int s = (rem >> 6) & 1;
    int t = (rem >> 7) % 3;
    int l = (rem >> 7) / 3;
    short8 h8, l8;
#pragma unroll
    for (int i = 0; i < 8; ++i) {
        int k = s * 32 + (lane >> 4) * 8 + i;
        int j = t * 16 + (lane & 15);
        float v = (k < NE) ? w[l * NE * NE + k * NE + j] : 0.0f;
        unsigned short hh = bf16_rne(v);
        float hf = __uint_as_float((unsigned)hh << 16);
        unsigned short ll = bf16_rne(v - hf);
        h8[i] = (short)hh;
        l8[i] = (short)ll;
    }
    hi[idx] = h8;
    lo[idx] = l8;
}

// ---------------- fused layer: async-pipelined edge agg + folded node transform ----------------
__global__ __launch_bounds__(64, 4) void layer_kernel(
    const float* __restrict__ hin,
    const int* __restrict__ colsrc,
    const int* __restrict__ ends,
    const int* __restrict__ cnt,
    float* __restrict__ hout,
    const short8* __restrict__ bhi,               // msg_w1 frags [3][2][64]
    const short8* __restrict__ blo,               // (unused in edge)
    const float* __restrict__ b1,                 // msg_b1
    const short8* __restrict__ f1hi, const short8* __restrict__ f1lo,   // F = W2*U1
    const float* __restrict__ b2u1v,
    const float* __restrict__ ub1,
    const short8* __restrict__ u2hi, const short8* __restrict__ u2lo,   // upd_w2
    const float* __restrict__ ub2,
    int N,
    int final_layer,
    const int* __restrict__ gid,
    const short8* __restrict__ rw1hi, const short8* __restrict__ rw1lo,
    const float* __restrict__ rb1, const float* __restrict__ rw2,
    const float* __restrict__ rb2, float* __restrict__ out)
{
    __shared__ float mytile[16][52];              // 16x48 agg tile (+pad)
    __shared__ float hdls[16][48];                // staged dst rows
    __shared__ int   slds[SLDS_CAP];              // staged edge indices
    __shared__ int   tlist[TLIST_CAP];            // flat tile list: nn<<16|remc<<11|eoff
    __shared__ float xst[PD][768];                // pipeline slots: 16 rows x 48 floats

    const int lane = threadIdx.x;
    const int n0   = blockIdx.x * 16;
    if (n0 >= N) return;

    const int m  = lane & 15;
    const int kb = lane >> 4;

    // ---- coop-stage 16 dst rows ----
    {
        const float4* sp = (const float4*)(hin + (size_t)n0 * NE);
        float4* dp = (float4*)hdls;
#pragma unroll
        for (int f = 0; f < 3; ++f) dp[lane + f * 64] = sp[lane + f * 64];
    }

    // ---- per-node metadata (lane m holds node m's values) ----
    const int mydeg = cnt[n0 + m];
    const int myend = ends[n0 + m];

    const int beg0 = __shfl(myend - mydeg, 0, 64);
    const int endL = __shfl(myend, 15, 64);
    const int tot  = endL - beg0;
    const bool uselds = (tot <= SLDS_CAP);
    if (uselds) {
        for (int i = lane; i < tot; i += 64) slds[i] = colsrc[beg0 + i];
    }

    // ---- build flat tile list (lanes 0..15, one node each) ----
    int ttot = 0;
    if (uselds) {
        const int ntile_m = (mydeg + 15) >> 4;
        int pref = ntile_m;
#pragma unroll
        for (int o = 1; o < 16; o <<= 1) {
            int u = __shfl_up(pref, o, 64);
            if ((lane & 15) >= o) pref += u;
        }
        ttot = __shfl(pref, 15, 64);
        if (lane < 16) {
            const int tstart = pref - ntile_m;
            const int begrel = (myend - mydeg) - beg0;
            for (int it = 0; it < ntile_m; ++it) {
                int rem = mydeg - it * 16;
                int remc = rem < 16 ? rem : 16;
                tlist[tstart + it] = (lane << 16) | (remc << 11) | (begrel + it * 16);
            }
        }
    }

    // ---- edge weight fragments (bf16 hi only) ----
    short8 bh[6];
#pragma unroll
    for (int i = 0; i < 6; ++i) bh[i] = bhi[i * 64 + lane];
    const float bb0 = b1[m], bb1 = b1[16 + m], bb2 = b1[32 + m];
    const float rbb0 = fmaxf(bb0, 0.0f), rbb1 = fmaxf(bb1, 0.0f), rbb2 = fmaxf(bb2, 0.0f);
    const float rbb_mine = (lane < 16) ? rbb0 : (lane < 32) ? rbb1 : rbb2;

    // ---- pre-zero agg rows (covers deg-0 nodes) ----
    {
        float4 z = make_float4(0, 0, 0, 0);
        float4* zp = (float4*)&mytile[lane >> 2][(lane & 3) * 12];
        zp[0] = z; zp[1] = z; zp[2] = z;
    }
    asm volatile("s_waitcnt vmcnt(0) lgkmcnt(0)" ::: "memory");  // stages + tlist visible

    // finalize helper (uniform call sites)
    float s0 = 0.0f, s1 = 0.0f, s2 = 0.0f;
    auto finalize = [&](int nn) {
        s0 += __shfl_xor(s0, 16, 64); s0 += __shfl_xor(s0, 32, 64);
        s1 += __shfl_xor(s1, 16, 64); s1 += __shfl_xor(s1, 32, 64);
        s2 += __shfl_xor(s2, 16, 64); s2 += __shfl_xor(s2, 32, 64);
        float t1v = __shfl(s1, lane & 15, 64);
        float t2v = __shfl(s2, lane & 15, 64);
        float val = (lane < 16) ? s0 : (lane < 32) ? t1v : t2v;
        int deg = __shfl(mydeg, nn, 64);
        float npad = (float)((((deg + 15) >> 4) << 4) - deg);
        val = fmaf(-npad, rbb_mine, val);
        if (lane < 48) mytile[nn][lane] = val;
    };

    if (uselds) {
        // -------- PD-deep async pipeline over flat tile stream --------
        const int r_iss = lane & 15, cg_iss = lane >> 4;
        auto issue_tile = [&](int ent, int slot, bool dummy) {
            int srow;
            if (dummy) {
                srow = N;
            } else {
                int eoff = ent & 2047;
                int remc = (ent >> 11) & 31;
                int sr = slds[eoff + r_iss];
                srow = (r_iss < remc) ? sr : N;
            }
            const float* gp = hin + (size_t)srow * NE + cg_iss * 4;
            float* lb = &xst[slot][0];
            gl_lds16(gp,      lb);        // floats [0,16) of each row
            gl_lds16(gp + 16, lb + 256);  // floats [16,32)
            gl_lds16(gp + 32, lb + 512);  // floats [32,48)
        };

        if (ttot > 0) {
            // prologue: fill PD slots (dummies if short)
#pragma unroll
            for (int i = 0; i < PD; ++i) {
                bool real = i < ttot;
                issue_tile(real ? tlist[i] : 0, i, !real);
            }

            int curn = -1;
            float4 d0a = make_float4(0,0,0,0), d0b = d0a, d1a = d0a, d1b = d0a;
            int slot = 0;
#pragma unroll 1
            for (int t = 0; t < ttot; ++t) {
                int ent = tlist[t];
                int nn = ent >> 16;
                if (nn != curn) {
                    if (curn >= 0) finalize(curn);
                    curn = nn; s0 = s1 = s2 = 0.0f;
                    const float* hr = hdls[nn];
                    d0a = *(const float4*)(hr + kb * 8);
                    d0b = *(const float4*)(hr + kb * 8 + 4);
                    if (kb < 2) {
                        d1a = *(const float4*)(hr + 32 + kb * 8);
                        d1b = *(const float4*)(hr + 32 + kb * 8 + 4);
                    }
                }

                asm volatile("s_waitcnt vmcnt(3)" ::: "memory");   // 3*(PD-1): tile t landed
                __builtin_amdgcn_sched_barrier(0);

                // read tile from slot: row m, float4 at chunk ch -> off = (ch>>2)*256+(ch&3)*64+m*4
                const float* xb = &xst[slot][0];
                const int o0 = (kb >> 1) * 256 + (kb & 1) * 128 + m * 4;  // chunk 2kb
                float4 a0 = *(const float4*)(xb + o0);
                float4 a1 = *(const float4*)(xb + o0 + 64);               // chunk 2kb+1
                float x0[8], x1[8];
                x0[0] = a0.x * d0a.x; x0[1] = a0.y * d0a.y; x0[2] = a0.z * d0a.z; x0[3] = a0.w * d0a.w;
                x0[4] = a1.x * d0b.x; x0[5] = a1.y * d0b.y; x0[6] = a1.z * d0b.z; x0[7] = a1.w * d0b.w;
                if (kb < 2) {
                    const int o2 = 512 + kb * 128 + m * 4;                // chunk 8+2kb
                    float4 a2 = *(const float4*)(xb + o2);
                    float4 a3 = *(const float4*)(xb + o2 + 64);
                    x1[0] = a2.x * d1a.x; x1[1] = a2.y * d1a.y; x1[2] = a2.z * d1a.z; x1[3] = a2.w * d1a.w;
                    x1[4] = a3.x * d1b.x; x1[5] = a3.y * d1b.y; x1[6] = a3.z * d1b.z; x1[7] = a3.w * d1b.w;
                } else {
#pragma unroll
                    for (int i = 0; i < 8; ++i) x1[i] = 0.0f;
                }

                short8 ah0 = cvt8(x0);
                short8 ah1 = cvt8(x1);
#pragma unroll
                for (int tt = 0; tt < 3; ++tt) {
                    floatx4 cc = {0.0f, 0.0f, 0.0f, 0.0f};
                    cc = __builtin_amdgcn_mfma_f32_16x16x32_bf16(ah0, bh[tt * 2 + 0], cc, 0, 0, 0);
                    cc = __builtin_amdgcn_mfma_f32_16x16x32_bf16(ah1, bh[tt * 2 + 1], cc, 0, 0, 0);
                    const float bb = (tt == 0) ? bb0 : (tt == 1) ? bb1 : bb2;
                    float ts = 0.0f;
#pragma unroll
                    for (int r = 0; r < 4; ++r)
                        ts += fmaxf(cc[r] + bb, 0.0f);
                    if (tt == 0) s0 += ts; else if (tt == 1) s1 += ts; else s2 += ts;
                }

                __builtin_amdgcn_sched_barrier(0);
                // refill this slot with tile t+PD (or dummy) to keep vmcnt uniform
                int t2 = t + PD;
                bool real = t2 < ttot;
                issue_tile(real ? tlist[t2] : 0, slot, !real);
                slot = (slot == PD - 1) ? 0 : slot + 1;
            }
            if (curn >= 0) finalize(curn);
            asm volatile("s_waitcnt vmcnt(0)" ::: "memory");  // drain dummies
        }
    } else {
        // -------- fallback: direct (r28-style) path, no staged indices --------
#pragma unroll 1
        for (int nn = 0; nn < 16; ++nn) {
            const int deg = __shfl(mydeg, nn, 64);
            const int end = __shfl(myend, nn, 64);
            const int beg = end - deg;
            const float* hr = hdls[nn];
            float4 d0a = *(const float4*)(hr + kb * 8);
            float4 d0b = *(const float4*)(hr + kb * 8 + 4);
            float4 d1a = make_float4(0, 0, 0, 0), d1b = d1a;
            if (kb < 2) {
                d1a = *(const float4*)(hr + 32 + kb * 8);
                d1b = *(const float4*)(hr + 32 + kb * 8 + 4);
            }
            s0 = s1 = s2 = 0.0f;
            const int ntile = (deg + 15) >> 4;
            for (int it = 0; it < ntile; ++it) {
                const int rem = deg - it * 16;
                int srow = (m < rem) ? colsrc[beg + it * 16 + m] : N;
                const float* hs = hin + (size_t)srow * NE + kb * 8;
                float x0[8], x1[8];
                {
                    float4 a0 = ((const float4*)hs)[0];
                    float4 a1 = ((const float4*)hs)[1];
                    x0[0] = a0.x * d0a.x; x0[1] = a0.y * d0a.y; x0[2] = a0.z * d0a.z; x0[3] = a0.w * d0a.w;
                    x0[4] = a1.x * d0b.x; x0[5] = a1.y * d0b.y; x0[6] = a1.z * d0b.z; x0[7] = a1.w * d0b.w;
                }
                if (kb < 2) {
                    float4 a0 = ((const float4*)(hs + 32))[0];
                    float4 a1 = ((const float4*)(hs + 32))[1];
                    x1[0] = a0.x * d1a.x; x1[1] = a0.y * d1a.y; x1[2] = a0.z * d1a.z; x1[3] = a0.w * d1a.w;
                    x1[4] = a1.x * d1b.x; x1[5] = a1.y * d1b.y; x1[6] = a1.z * d1b.z; x1[7] = a1.w * d1b.w;
                } else {
#pragma unroll
                    for (int i = 0; i < 8; ++i) x1[i] = 0.0f;
                }
                short8 ah0 = cvt8(x0);
                short8 ah1 = cvt8(x1);
#pragma unroll
                for (int tt = 0; tt < 3; ++tt) {
                    floatx4 cc = {0.0f, 0.0f, 0.0f, 0.0f};
                    cc = __builtin_amdgcn_mfma_f32_16x16x32_bf16(ah0, bh[tt * 2 + 0], cc, 0, 0, 0);
                    cc = __builtin_amdgcn_mfma_f32_16x16x32_bf16(ah1, bh[tt * 2 + 1], cc, 0, 0, 0);
                    const float bb = (tt == 0) ? bb0 : (tt == 1) ? bb1 : bb2;
                    float ts = 0.0f;
#pragma unroll
                    for (int r = 0; r < 4; ++r)
                        ts += fmaxf(cc[r] + bb, 0.0f);
                    if (tt == 0) s0 += ts; else if (tt == 1) s1 += ts; else s2 += ts;
                }
            }
            finalize(nn);
        }
    }
    asm volatile("s_waitcnt lgkmcnt(0)" ::: "memory");

    // ---------------- node phase: 2 GEMMs (folded, full hi/lo) + fused readout ----------------
    float c0[8], c1[8];
    {
        const float* row = &mytile[m][0];
        *(float4*)(c0)     = *(const float4*)(row + kb * 8);
        *(float4*)(c0 + 4) = *(const float4*)(row + kb * 8 + 4);
        if (kb < 2) {
            *(float4*)(c1)     = *(const float4*)(row + 32 + kb * 8);
            *(float4*)(c1 + 4) = *(const float4*)(row + 32 + kb * 8 + 4);
        } else {
#pragma unroll
            for (int i = 0; i < 8; ++i) c1[i] = 0.0f;
        }
    }
    asm volatile("s_waitcnt lgkmcnt(0)" ::: "memory");
    short8 ah0, al0, ah1, al1;
    split8p(c0, ah0, al0);
    split8p(c1, ah1, al1);

    floatx4 acc[3];
    gemm3(ah0, al0, ah1, al1, f1hi, f1lo, lane, acc);   // agg @ F
    {
        float dj[3], bj[3];
#pragma unroll
        for (int t = 0; t < 3; ++t) { dj[t] = b2u1v[t * 16 + m]; bj[t] = ub1[t * 16 + m]; }
#pragma unroll
        for (int r = 0; r < 4; ++r) {
            float fd = (float)__shfl(mydeg, kb * 4 + r, 64);
#pragma unroll
            for (int t = 0; t < 3; ++t)
                acc[t][r] = fmaxf(fmaf(fd, dj[t], acc[t][r]) + bj[t], 0.0f);
        }
    }

    // transpose C->A, GEMM2: T @ U2
#pragma unroll
    for (int t = 0; t < 3; ++t)
#pragma unroll
        for (int r = 0; r < 4; ++r)
            mytile[kb * 4 + r][t * 16 + m] = acc[t][r];
    asm volatile("s_waitcnt lgkmcnt(0)" ::: "memory");
    {
        const float* row = &mytile[m][0];
        *(float4*)(c0)     = *(const float4*)(row + kb * 8);
        *(float4*)(c0 + 4) = *(const float4*)(row + kb * 8 + 4);
        if (kb < 2) {
            *(float4*)(c1)     = *(const float4*)(row + 32 + kb * 8);
            *(float4*)(c1 + 4) = *(const float4*)(row + 32 + kb * 8 + 4);
        } else {
#pragma unroll
            for (int i = 0; i < 8; ++i) c1[i] = 0.0f;
        }
    }
    asm volatile("s_waitcnt lgkmcnt(0)" ::: "memory");
    split8p(c0, ah0, al0);
    split8p(c1, ah1, al1);
    gemm3(ah0, al0, ah1, al1, u2hi, u2lo, lane, acc);

    // out_h = hin + ub2 + acc  (residual from staged hdls)
    {
        float bj[3];
#pragma unroll
        for (int t = 0; t < 3; ++t) bj[t] = ub2[t * 16 + m];
#pragma unroll
        for (int r = 0; r < 4; ++r) {
#pragma unroll
            for (int t = 0; t < 3; ++t)
                acc[t][r] += hdls[kb * 4 + r][t * 16 + m] + bj[t];
        }
    }

    if (!final_layer) {
#pragma unroll
        for (int r = 0; r < 4; ++r) {
            const size_t row = (size_t)(n0 + kb * 4 + r) * NE;
#pragma unroll
            for (int t = 0; t < 3; ++t)
                hout[row + t * 16 + m] = acc[t][r];
        }
        return;
    }

    // fused readout
#pragma unroll
    for (int t = 0; t < 3; ++t)
#pragma unroll
        for (int r = 0; r < 4; ++r)
            mytile[kb * 4 + r][t * 16 + m] = acc[t][r];
    asm volatile("s_waitcnt lgkmcnt(0)" ::: "memory");
    {
        const float* row = &mytile[m][0];
        *(float4*)(c0)     = *(const float4*)(row + kb * 8);
        *(float4*)(c0 + 4) = *(const float4*)(row + kb * 8 + 4);
        if (kb < 2) {
            *(float4*)(c1)     = *(const float4*)(row + 32 + kb * 8);
            *(float4*)(c1 + 4) = *(const float4*)(row + 32 + kb * 8 + 4);
        } else {
#pragma unroll
            for (int i = 0; i < 8; ++i) c1[i] = 0.0f;
        }
    }
    split8p(c0, ah0, al0);
    split8p(c1, ah1, al1);
    gemm3(ah0, al0, ah1, al1, rw1hi, rw1lo, lane, acc);

    float p[4] = {0.0f, 0.0f, 0.0f, 0.0f};
    {
        float bj[3], wj[3];
#pragma unroll
        for (int t = 0; t < 3; ++t) { bj[t] = rb1[t * 16 + m]; wj[t] = rw2[t * 16 + m]; }
#pragma unroll
        for (int t = 0; t < 3; ++t)
#pragma unroll
            for (int r = 0; r < 4; ++r)
                p[r] = fmaf(fmaxf(acc[t][r] + bj[t], 0.0f), wj[t], p[r]);
    }
#pragma unroll
    for (int o = 1; o < 16; o <<= 1) {
#pragma unroll
        for (int r = 0; r < 4; ++r) p[r] += __shfl_xor(p[r], o, 16);
    }
    if (m == 0) {
        float b2v = rb2[0];
#pragma unroll
        for (int r = 0; r < 4; ++r) {
            int n = n0 + kb * 4 + r;
            atomicAdd(out + gid[n], p[r] + b2v);
        }
    }
}

extern "C" void kernel_launch(void* const* d_in, const int* in_sizes, int n_in,
                              void* d_out, int out_size, void* d_ws, size_t ws_size,
                              hipStream_t stream) {
    const int*   AtomicNum = (const int*)  d_in[0];
    const int*   Edge      = (const int*)  d_in[1];
    const int*   graph_id  = (const int*)  d_in[2];
    const float* emb       = (const float*)d_in[3];
    const float* msg_w1    = (const float*)d_in[4];
    const float* msg_b1    = (const float*)d_in[5];
    const float* msg_w2    = (const float*)d_in[6];
    const float* msg_b2    = (const float*)d_in[7];
    const float* upd_w1    = (const float*)d_in[8];
    const float* upd_b1    = (const float*)d_in[9];
    const float* upd_w2    = (const float*)d_in[10];
    const float* upd_b2    = (const float*)d_in[11];
    const float* ro_w1     = (const float*)d_in[12];
    const float* ro_b1     = (const float*)d_in[13];
    const float* ro_w2     = (const float*)d_in[14];
    const float* ro_b2     = (const float*)d_in[15];

    const int N = in_sizes[0];          // 100000 (divisible by 16)
    const int E = in_sizes[1] / 2;      // 1600000
    const int* src = Edge;
    const int* dst = Edge + E;
    const int NB = (N + 255) >> NB_SH;  // 391 dst-buckets
    const int NBLK = (N + 1023) / 1024; // 98 scan blocks

    // workspace layout (~46 MB); h/h2 have N+1 rows (row N = zero pad row).
    float*  h    = (float*)d_ws;                       // (N+1)*48
    float*  h2   = h  + (size_t)(N + 1) * NE;          // (N+1)*48
    int*    cnt  = (int*)(h2 + (size_t)(N + 1) * NE);  // N
    int*    offs = cnt + N;                            // N (end offsets after partB)
    int*    colsrc = offs + N;                         // E
    short8* whi  = (short8*)(colsrc + E);              // 3*2304 + 384
    short8* wlo  = whi + (3 * 2304 + 384);
    int*    gpos = (int*)(wlo + (3 * 2304 + 384));     // NB
    int*    bsum = gpos + NB;                          // NBLK
    float*  foldF = (float*)(bsum + NBLK);             // 6*48*48
    float*  b2u1  = foldF + 6 * NE * NE;               // 6*48
    int2*   pairbuf = (int2*)h2;                       // E (aliases h2)

    hipMemsetAsync(d_out, 0, (size_t)out_size * sizeof(float), stream);
    hipMemsetAsync(cnt, 0, (size_t)N * sizeof(int), stream);
    hipMemsetAsync(h  + (size_t)N * NE, 0, NE * sizeof(float), stream);  // zero pad row
    hipMemsetAsync(h2 + (size_t)N * NE, 0, NE * sizeof(float), stream);  // zero pad row

    int n4 = N * 12;
    embed_kernel<<<(n4 + 255) / 256, 256, 0, stream>>>(AtomicNum, emb, h, n4);

    fold_kernel<<<(6 * NE * NE + 6 * NE + 255) / 256, 256, 0, stream>>>(
        msg_w2, upd_w1, msg_b2, foldF, b2u1);

    hist_kernel<<<(E + 255) / 256, 256, 0, stream>>>(dst, cnt, E);
    scansum_kernel<<<NBLK, 256, 0, stream>>>(cnt, bsum, N);
    scanb_kernel<<<1, 256, 0, stream>>>(bsum, NBLK);
    scanfix_kernel<<<NBLK, 1024, 0, stream>>>(cnt, bsum, offs, gpos, N);
    partA_kernel<<<(E + 2047) / 2048, 256, 0, stream>>>(src, dst, gpos, pairbuf, E, NB);
    partB_kernel<<<(E + 255) / 256, 256, 0, stream>>>(pairbuf, offs, colsrc, E);

    pack_all_kernel<<<(3 * 2304 + 384 + 255) / 256, 256, 0, stream>>>(
        msg_w1, foldF, upd_w2, ro_w1, whi, wlo);

    const float* hin = h;
    float* hout = h2;
    for (int l = 0; l < 6; ++l) {
        layer_kernel<<<N / 16, 64, 0, stream>>>(
            hin, colsrc, offs, cnt, hout,
            whi + 0 * 2304 + (size_t)l * 384, wlo + 0 * 2304 + (size_t)l * 384,
            msg_b1 + (size_t)l * NE,
            whi + 1 * 2304 + (size_t)l * 384, wlo + 1 * 2304 + (size_t)l * 384,
            b2u1 + (size_t)l * NE,
            upd_b1 + (size_t)l * NE,
            whi + 2 * 2304 + (size_t)l * 384, wlo + 2 * 2304 + (size_t)l * 384,
            upd_b2 + (size_t)l * NE,
            N,
            (l == 5) ? 1 : 0,
            graph_id,
            whi + 3 * 2304, wlo + 3 * 2304,
            ro_b1, ro_w2, ro_b2, (float*)d_out);
        const float* tmp = hin; hin = hout; hout = (float*)tmp;
    }
}

// Round 13
// 704.920 us; speedup vs baseline: 1.0844x; 1.0800x over previous
//
#include <hip/hip_runtime.h>
#include <hip/hip_bf16.h>

// VanillaMPNN on MI355X — round 31: gather from a bf16 shadow of h.
// r29/r30 falsified in-wave gather pipelining (LDS/occupancy cost > win);
// r28 structure is the keeper. Remaining chain term: 21 tiles x ~650cy gather.
// This round shrinks the latency itself: keep h fp32 (dst rows, residual,
// node phase unchanged) + maintain a bf16 shadow hb (9.6MB): gather rows are
// 96B (2 lines vs 3-4), working set halves -> more L2 hits; the short8 load
// IS the MFMA A-fragment (unpack = shift/mask, 2 VALU/elem). Shadow written
// for free in epilogue/embed. Extra rounding only on the edge src operand:
// absmax predicted ~1600-2000 vs threshold 2928.

#define NE 48
#define NB_SH 8                       // 256 nodes per bucket
#define SLDS_CAP 1024                 // staged edge indices per wave

typedef __attribute__((ext_vector_type(8))) short short8;
typedef __attribute__((ext_vector_type(4))) float floatx4;

__device__ __forceinline__ unsigned short bf16_rne(float v) {
    unsigned u = __float_as_uint(v);
    u += 0x7FFFu + ((u >> 16) & 1u);
    return (unsigned short)(u >> 16);
}

// packed hi/lo split: 8 fp32 -> 8 bf16 hi + 8 bf16 lo (RNE both)
__device__ __forceinline__ void split8p(const float* __restrict__ x, short8& hi, short8& lo) {
    union { unsigned u[4]; short8 s; } H, L;
#pragma unroll
    for (int i = 0; i < 4; ++i) {
        float a = x[2 * i], b = x[2 * i + 1];
        __hip_bfloat162 h2 = __float22bfloat162_rn(make_float2(a, b));
        unsigned h = *reinterpret_cast<unsigned*>(&h2);
        float ra = a - __uint_as_float(h << 16);
        float rb = b - __uint_as_float(h & 0xFFFF0000u);
        __hip_bfloat162 l2 = __float22bfloat162_rn(make_float2(ra, rb));
        H.u[i] = h;
        L.u[i] = *reinterpret_cast<unsigned*>(&l2);
    }
    hi = H.s; lo = L.s;
}

// plain pack: 8 fp32 -> 8 bf16 (RNE), no residual
__device__ __forceinline__ short8 cvt8(const float* __restrict__ x) {
    union { unsigned u[4]; short8 s; } H;
#pragma unroll
    for (int i = 0; i < 4; ++i) {
        __hip_bfloat162 h2 = __float22bfloat162_rn(make_float2(x[2 * i], x[2 * i + 1]));
        H.u[i] = *reinterpret_cast<unsigned*>(&h2);
    }
    return H.s;
}

// 3 j-tiles, 6 MFMA each: acc[t] = split3(A) @ B[t]
__device__ __forceinline__ void gemm3(const short8& ah0, const short8& al0,
                                      const short8& ah1, const short8& al1,
                                      const short8* __restrict__ hi,
                                      const short8* __restrict__ lo,
                                      int lane, floatx4* acc) {
#pragma unroll
    for (int t = 0; t < 3; ++t) {
        short8 bh0 = hi[(t * 2 + 0) * 64 + lane];
        short8 bh1 = hi[(t * 2 + 1) * 64 + lane];
        short8 bl0 = lo[(t * 2 + 0) * 64 + lane];
        short8 bl1 = lo[(t * 2 + 1) * 64 + lane];
        floatx4 c = {0.0f, 0.0f, 0.0f, 0.0f};
        c = __builtin_amdgcn_mfma_f32_16x16x32_bf16(ah0, bh0, c, 0, 0, 0);
        c = __builtin_amdgcn_mfma_f32_16x16x32_bf16(ah1, bh1, c, 0, 0, 0);
        c = __builtin_amdgcn_mfma_f32_16x16x32_bf16(al0, bh0, c, 0, 0, 0);
        c = __builtin_amdgcn_mfma_f32_16x16x32_bf16(al1, bh1, c, 0, 0, 0);
        c = __builtin_amdgcn_mfma_f32_16x16x32_bf16(ah0, bl0, c, 0, 0, 0);
        c = __builtin_amdgcn_mfma_f32_16x16x32_bf16(ah1, bl1, c, 0, 0, 0);
        acc[t] = c;
    }
}

// ---------------- embed: fp32 h + bf16 shadow ----------------
__global__ __launch_bounds__(256) void embed_kernel(const int* __restrict__ an,
                                                    const float* __restrict__ emb,
                                                    float* __restrict__ h,
                                                    unsigned short* __restrict__ hb, int n4) {
    int i = blockIdx.x * 256 + threadIdx.x;
    if (i >= n4) return;
    int n = i / 12, q = i - n * 12;
    float4 v = ((const float4*)emb)[an[n] * 12 + q];
    ((float4*)h)[i] = v;
    union { unsigned short s[4]; uint2 u; } P;
    P.s[0] = bf16_rne(v.x); P.s[1] = bf16_rne(v.y);
    P.s[2] = bf16_rne(v.z); P.s[3] = bf16_rne(v.w);
    *(uint2*)(hb + (size_t)n * NE + q * 4) = P.u;
}

// ---------------- fold: F = msg_w2 @ upd_w1, b2u1 = msg_b2 @ upd_w1 ----------------
__global__ __launch_bounds__(256) void fold_kernel(const float* __restrict__ w2,
                                                   const float* __restrict__ u1,
                                                   const float* __restrict__ b2,
                                                   float* __restrict__ F,
                                                   float* __restrict__ b2u1) {
    int idx = blockIdx.x * 256 + threadIdx.x;
    if (idx < 6 * NE * NE) {
        int l = idx / (NE * NE);
        int r = idx - l * NE * NE;
        int k = r / NE, j = r - (r / NE) * NE;
        const float* wrow = w2 + (size_t)l * NE * NE + k * NE;
        const float* ucol = u1 + (size_t)l * NE * NE + j;
        float s = 0.0f;
#pragma unroll 8
        for (int q = 0; q < NE; ++q) s = fmaf(wrow[q], ucol[q * NE], s);
        F[idx] = s;
    } else if (idx < 6 * NE * NE + 6 * NE) {
        int r = idx - 6 * NE * NE;
        int l = r / NE, j = r - l * NE;
        const float* bv = b2 + (size_t)l * NE;
        const float* ucol = u1 + (size_t)l * NE * NE + j;
        float s = 0.0f;
#pragma unroll 8
        for (int q = 0; q < NE; ++q) s = fmaf(bv[q], ucol[q * NE], s);
        b2u1[r] = s;
    }
}

// ---------------- CSR build ----------------
__global__ __launch_bounds__(256) void hist_kernel(const int* __restrict__ dst,
                                                   int* __restrict__ cnt, int E) {
    int e = blockIdx.x * 256 + threadIdx.x;
    if (e < E) atomicAdd(&cnt[dst[e]], 1);
}

__global__ __launch_bounds__(256) void scansum_kernel(const int* __restrict__ cnt,
                                                      int* __restrict__ bsum, int N) {
    __shared__ int sw[4];
    const int tid = threadIdx.x, lane = tid & 63, wid = tid >> 6;
    int base = blockIdx.x * 1024;
    int v = 0;
#pragma unroll
    for (int k = 0; k < 4; ++k) {
        int i = base + k * 256 + tid;
        v += (i < N) ? cnt[i] : 0;
    }
#pragma unroll
    for (int o = 1; o < 64; o <<= 1) v += __shfl_xor(v, o, 64);
    if (lane == 0) sw[wid] = v;
    __syncthreads();
    if (tid == 0) bsum[blockIdx.x] = sw[0] + sw[1] + sw[2] + sw[3];
}

__global__ __launch_bounds__(256) void scanb_kernel(int* __restrict__ bsum, int nblk) {
    __shared__ int s[256];
    int tid = threadIdx.x;
    s[tid] = (tid < nblk) ? bsum[tid] : 0;
    __syncthreads();
    if (tid == 0) {
        int run = 0;
        for (int i = 0; i < nblk; ++i) { int t = s[i]; s[i] = run; run += t; }
    }
    __syncthreads();
    if (tid < nblk) bsum[tid] = s[tid];
}

__global__ __launch_bounds__(1024) void scanfix_kernel(const int* __restrict__ cnt,
                                                       const int* __restrict__ bsum,
                                                       int* __restrict__ offs,
                                                       int* __restrict__ gpos, int N) {
    __shared__ int swave[16];
    const int tid = threadIdx.x, lane = tid & 63, wid = tid >> 6;
    int i = blockIdx.x * 1024 + tid;
    int orig = (i < N) ? cnt[i] : 0;
    int v = orig;
#pragma unroll
    for (int off = 1; off < 64; off <<= 1) {
        int u = __shfl_up(v, off, 64);
        if (lane >= off) v += u;
    }
    if (lane == 63) swave[wid] = v;
    __syncthreads();
    if (wid == 0) {
        int w = (lane < 16) ? swave[lane] : 0;
#pragma unroll
        for (int off = 1; off < 16; off <<= 1) {
            int u = __shfl_up(w, off, 64);
            if (lane >= off) w += u;
        }
        if (lane < 16) swave[lane] = w;
    }
    __syncthreads();
    int prefix = (wid > 0) ? swave[wid - 1] : 0;
    int val = bsum[blockIdx.x] + prefix + v - orig;
    if (i < N) {
        offs[i] = val;
        if ((i & 255) == 0) gpos[i >> 8] = val;
    }
}

__global__ __launch_bounds__(256) void partA_kernel(const int* __restrict__ src,
                                                    const int* __restrict__ dst,
                                                    int* __restrict__ gpos,
                                                    int2* __restrict__ pairbuf,
                                                    int E, int NB) {
    __shared__ int lhist[512];
    __shared__ int lbase[512];
    const int tid = threadIdx.x;
    for (int i = tid; i < NB; i += 256) lhist[i] = 0;
    __syncthreads();
    const int base = blockIdx.x * 2048;
    int ssrc[8], sdst[8], rnk[8];
#pragma unroll
    for (int k = 0; k < 8; ++k) {
        int e = base + k * 256 + tid;
        if (e < E) {
            ssrc[k] = src[e]; sdst[k] = dst[e];
            rnk[k] = atomicAdd(&lhist[sdst[k] >> NB_SH], 1);
        }
    }
    __syncthreads();
    for (int i = tid; i < NB; i += 256) {
        int c = lhist[i];
        lbase[i] = c ? atomicAdd(&gpos[i], c) : 0;
    }
    __syncthreads();
#pragma unroll
    for (int k = 0; k < 8; ++k) {
        int e = base + k * 256 + tid;
        if (e < E)
            pairbuf[lbase[sdst[k] >> NB_SH] + rnk[k]] = make_int2(ssrc[k], sdst[k]);
    }
}

__global__ __launch_bounds__(256) void partB_kernel(const int2* __restrict__ pairbuf,
                                                    int* __restrict__ offs,   // becomes END offsets
                                                    int* __restrict__ colsrc, int E) {
    int e = blockIdx.x * 256 + threadIdx.x;
    if (e < E) {
        int2 p = pairbuf[e];
        int pos = atomicAdd(&offs[p.y], 1);
        colsrc[pos] = p.x;
    }
}

// ---------------- pack 4 weight families -> B-fragment tables ----------------
__global__ __launch_bounds__(256) void pack_all_kernel(const float* __restrict__ w0,
                                                       const float* __restrict__ w1m,
                                                       const float* __restrict__ w2m,
                                                       const float* __restrict__ w3m,
                                                       short8* __restrict__ hi,
                                                       short8* __restrict__ lo) {
    int idx = blockIdx.x * 256 + threadIdx.x;
    if (idx >= 3 * 2304 + 384) return;
    int slot = idx / 2304;
    int rem  = idx - slot * 2304;
    const float* w = (slot == 0) ? w0 : (slot == 1) ? w1m : (slot == 2) ? w2m : w3m;
    int lane = rem & 63;
    int s = (rem >> 6) & 1;
    int t = (rem >> 7) % 3;
    int l = (rem >> 7) / 3;
    short8 h8, l8;
#pragma unroll
    for (int i = 0; i < 8; ++i) {
        int k = s * 32 + (lane >> 4) * 8 + i;
        int j = t * 16 + (lane & 15);
        float v = (k < NE) ? w[l * NE * NE + k * NE + j] : 0.0f;
        unsigned short hh = bf16_rne(v);
        float hf = __uint_as_float((unsigned)hh << 16);
        unsigned short ll = bf16_rne(v - hf);
        h8[i] = (short)hh;
        l8[i] = (short)ll;
    }
    hi[idx] = h8;
    lo[idx] = l8;
}

// ---------------- fused layer: bf16-shadow gather + folded node transform ----------------
__global__ __launch_bounds__(64, 4) void layer_kernel(
    const float* __restrict__ hin,
    const unsigned short* __restrict__ hbin,      // bf16 shadow of hin
    const int* __restrict__ colsrc,
    const int* __restrict__ ends,
    const int* __restrict__ cnt,
    float* __restrict__ hout,
    unsigned short* __restrict__ hbout,           // bf16 shadow of hout
    const short8* __restrict__ bhi,               // msg_w1 frags [3][2][64]
    const float* __restrict__ b1,                 // msg_b1
    const short8* __restrict__ f1hi, const short8* __restrict__ f1lo,   // F = W2*U1
    const float* __restrict__ b2u1v,
    const float* __restrict__ ub1,
    const short8* __restrict__ u2hi, const short8* __restrict__ u2lo,   // upd_w2
    const float* __restrict__ ub2,
    int N,
    int final_layer,
    const int* __restrict__ gid,
    const short8* __restrict__ rw1hi, const short8* __restrict__ rw1lo,
    const float* __restrict__ rb1, const float* __restrict__ rw2,
    const float* __restrict__ rb2, float* __restrict__ out)
{
    __shared__ float mytile[16][52];              // 16x48 agg tile (+pad)
    __shared__ float hdls[16][48];                // staged dst rows (fp32)
    __shared__ int   slds[SLDS_CAP];              // staged edge indices
    const int lane = threadIdx.x;
    const int n0   = blockIdx.x * 16;
    if (n0 >= N) return;

    const int m  = lane & 15;
    const int kb = lane >> 4;

    // ---- coop-stage 16 dst rows into LDS (one latency exposure) ----
    {
        const float4* sp = (const float4*)(hin + (size_t)n0 * NE);
        float4* dp = (float4*)hdls;
#pragma unroll
        for (int f = 0; f < 3; ++f) dp[lane + f * 64] = sp[lane + f * 64];
    }

    // ---- per-node metadata in registers (lane m holds node m's values) ----
    const int mydeg = cnt[n0 + m];
    const int myend = ends[n0 + m];

    // ---- coop-stage the wave's contiguous edge-index range ----
    const int beg0 = __shfl(myend - mydeg, 0, 64);
    const int endL = __shfl(myend, 15, 64);
    const int tot  = endL - beg0;
    const bool uselds = (tot <= SLDS_CAP);
    if (uselds) {
        for (int i = lane; i < tot; i += 64) slds[i] = colsrc[beg0 + i];
    }

    // ---- edge weight fragments in registers (bf16 hi only) ----
    short8 bh[6];
#pragma unroll
    for (int i = 0; i < 6; ++i) bh[i] = bhi[i * 64 + lane];
    const float bb0 = b1[m], bb1 = b1[16 + m], bb2 = b1[32 + m];
    const float rbb0 = fmaxf(bb0, 0.0f), rbb1 = fmaxf(bb1, 0.0f), rbb2 = fmaxf(bb2, 0.0f);
    const float rbb_mine = (lane < 16) ? rbb0 : (lane < 32) ? rbb1 : rbb2;

    asm volatile("s_waitcnt vmcnt(0) lgkmcnt(0)" ::: "memory");  // stages complete

    // ---------------- edge phase: per-node complete aggregation (bf16 shadow gather) ----------------
#pragma unroll 1
    for (int nn = 0; nn < 16; ++nn) {
        const int deg = __shfl(mydeg, nn, 64);
        const int end = __shfl(myend, nn, 64);
        const int beg = end - deg;

        const float* hr = hdls[nn];               // staged dst row (LDS broadcast)
        float4 d0a = *(const float4*)(hr + kb * 8);
        float4 d0b = *(const float4*)(hr + kb * 8 + 4);
        float4 d1a = make_float4(0, 0, 0, 0), d1b = d1a;
        if (kb < 2) {
            d1a = *(const float4*)(hr + 32 + kb * 8);
            d1b = *(const float4*)(hr + 32 + kb * 8 + 4);
        }

        float s0 = 0.0f, s1 = 0.0f, s2 = 0.0f;
        const int ntile = (deg + 15) >> 4;

        for (int it = 0; it < ntile; ++it) {
            const int rem = deg - it * 16;
            int srow;
            if (uselds) srow = (m < rem) ? slds[beg - beg0 + it * 16 + m] : N;
            else        srow = (m < rem) ? colsrc[beg + it * 16 + m] : N;
            const unsigned short* hs = hbin + (size_t)srow * NE;

            // bf16 shadow row: the short8 IS the A-fragment layout; unpack+scale
            union { short8 s; unsigned u[4]; } A0, A1;
            A0.s = *(const short8*)(hs + kb * 8);
            float x0[8], x1[8];
            x0[0] = __uint_as_float(A0.u[0] << 16)         * d0a.x;
            x0[1] = __uint_as_float(A0.u[0] & 0xFFFF0000u) * d0a.y;
            x0[2] = __uint_as_float(A0.u[1] << 16)         * d0a.z;
            x0[3] = __uint_as_float(A0.u[1] & 0xFFFF0000u) * d0a.w;
            x0[4] = __uint_as_float(A0.u[2] << 16)         * d0b.x;
            x0[5] = __uint_as_float(A0.u[2] & 0xFFFF0000u) * d0b.y;
            x0[6] = __uint_as_float(A0.u[3] << 16)         * d0b.z;
            x0[7] = __uint_as_float(A0.u[3] & 0xFFFF0000u) * d0b.w;
            if (kb < 2) {
                A1.s = *(const short8*)(hs + 32 + kb * 8);
                x1[0] = __uint_as_float(A1.u[0] << 16)         * d1a.x;
                x1[1] = __uint_as_float(A1.u[0] & 0xFFFF0000u) * d1a.y;
                x1[2] = __uint_as_float(A1.u[1] << 16)         * d1a.z;
                x1[3] = __uint_as_float(A1.u[1] & 0xFFFF0000u) * d1a.w;
                x1[4] = __uint_as_float(A1.u[2] << 16)         * d1b.x;
                x1[5] = __uint_as_float(A1.u[2] & 0xFFFF0000u) * d1b.y;
                x1[6] = __uint_as_float(A1.u[3] << 16)         * d1b.z;
                x1[7] = __uint_as_float(A1.u[3] & 0xFFFF0000u) * d1b.w;
            } else {
#pragma unroll
                for (int i = 0; i < 8; ++i) x1[i] = 0.0f;
            }

            short8 ah0 = cvt8(x0);
            short8 ah1 = cvt8(x1);

#pragma unroll
            for (int t = 0; t < 3; ++t) {
                floatx4 cc = {0.0f, 0.0f, 0.0f, 0.0f};
                cc = __builtin_amdgcn_mfma_f32_16x16x32_bf16(ah0, bh[t * 2 + 0], cc, 0, 0, 0);
                cc = __builtin_amdgcn_mfma_f32_16x16x32_bf16(ah1, bh[t * 2 + 1], cc, 0, 0, 0);
                const float bb = (t == 0) ? bb0 : (t == 1) ? bb1 : bb2;
                float ts = 0.0f;
#pragma unroll
                for (int r = 0; r < 4; ++r)
                    ts += fmaxf(cc[r] + bb, 0.0f);     // pad rows contribute relu(bb)
                if (t == 0) s0 += ts; else if (t == 1) s1 += ts; else s2 += ts;
            }
        }

        s0 += __shfl_xor(s0, 16, 64); s0 += __shfl_xor(s0, 32, 64);
        s1 += __shfl_xor(s1, 16, 64); s1 += __shfl_xor(s1, 32, 64);
        s2 += __shfl_xor(s2, 16, 64); s2 += __shfl_xor(s2, 32, 64);

        float t1v = __shfl(s1, lane & 15, 64);
        float t2v = __shfl(s2, lane & 15, 64);
        float val = (lane < 16) ? s0 : (lane < 32) ? t1v : t2v;
        // exact pad correction, applied ONCE after the reduction
        const float npad = (float)(ntile * 16 - deg);
        val = fmaf(-npad, rbb_mine, val);
        if (lane < 48) mytile[nn][lane] = val;
    }
    asm volatile("s_waitcnt lgkmcnt(0)" ::: "memory");

    // ---------------- node phase: 2 GEMMs (folded, full hi/lo) + fused readout ----------------
    float c0[8], c1[8];
    {
        const float* row = &mytile[m][0];
        *(float4*)(c0)     = *(const float4*)(row + kb * 8);
        *(float4*)(c0 + 4) = *(const float4*)(row + kb * 8 + 4);
        if (kb < 2) {
            *(float4*)(c1)     = *(const float4*)(row + 32 + kb * 8);
            *(float4*)(c1 + 4) = *(const float4*)(row + 32 + kb * 8 + 4);
        } else {
#pragma unroll
            for (int i = 0; i < 8; ++i) c1[i] = 0.0f;
        }
    }
    asm volatile("s_waitcnt lgkmcnt(0)" ::: "memory");
    short8 ah0, al0, ah1, al1;
    split8p(c0, ah0, al0);
    split8p(c1, ah1, al1);

    floatx4 acc[3];
    gemm3(ah0, al0, ah1, al1, f1hi, f1lo, lane, acc);   // agg @ F
    {
        float dj[3], bj[3];
#pragma unroll
        for (int t = 0; t < 3; ++t) { dj[t] = b2u1v[t * 16 + m]; bj[t] = ub1[t * 16 + m]; }
#pragma unroll
        for (int r = 0; r < 4; ++r) {
            float fd = (float)__shfl(mydeg, kb * 4 + r, 64);
#pragma unroll
            for (int t = 0; t < 3; ++t)
                acc[t][r] = fmaxf(fmaf(fd, dj[t], acc[t][r]) + bj[t], 0.0f);
        }
    }

    // transpose C->A, GEMM2: T @ U2
#pragma unroll
    for (int t = 0; t < 3; ++t)
#pragma unroll
        for (int r = 0; r < 4; ++r)
            mytile[kb * 4 + r][t * 16 + m] = acc[t][r];
    asm volatile("s_waitcnt lgkmcnt(0)" ::: "memory");
    {
        const float* row = &mytile[m][0];
        *(float4*)(c0)     = *(const float4*)(row + kb * 8);
        *(float4*)(c0 + 4) = *(const float4*)(row + kb * 8 + 4);
        if (kb < 2) {
            *(float4*)(c1)     = *(const float4*)(row + 32 + kb * 8);
            *(float4*)(c1 + 4) = *(const float4*)(row + 32 + kb * 8 + 4);
        } else {
#pragma unroll
            for (int i = 0; i < 8; ++i) c1[i] = 0.0f;
        }
    }
    asm volatile("s_waitcnt lgkmcnt(0)" ::: "memory");
    split8p(c0, ah0, al0);
    split8p(c1, ah1, al1);
    gemm3(ah0, al0, ah1, al1, u2hi, u2lo, lane, acc);

    // out_h = hin + ub2 + acc  (residual from staged hdls)
    {
        float bj[3];
#pragma unroll
        for (int t = 0; t < 3; ++t) bj[t] = ub2[t * 16 + m];
#pragma unroll
        for (int r = 0; r < 4; ++r) {
#pragma unroll
            for (int t = 0; t < 3; ++t)
                acc[t][r] += hdls[kb * 4 + r][t * 16 + m] + bj[t];
        }
    }

    if (!final_layer) {
#pragma unroll
        for (int r = 0; r < 4; ++r) {
            const size_t row = (size_t)(n0 + kb * 4 + r) * NE;
#pragma unroll
            for (int t = 0; t < 3; ++t) {
                float v = acc[t][r];
                hout[row + t * 16 + m] = v;
                hbout[row + t * 16 + m] = bf16_rne(v);   // bf16 shadow
            }
        }
        return;
    }

    // fused readout: y = relu(h @ ro_w1 + rb1) . rw2 + rb2 ; segment-sum by gid
#pragma unroll
    for (int t = 0; t < 3; ++t)
#pragma unroll
        for (int r = 0; r < 4; ++r)
            mytile[kb * 4 + r][t * 16 + m] = acc[t][r];
    asm volatile("s_waitcnt lgkmcnt(0)" ::: "memory");
    {
        const float* row = &mytile[m][0];
        *(float4*)(c0)     = *(const float4*)(row + kb * 8);
        *(float4*)(c0 + 4) = *(const float4*)(row + kb * 8 + 4);
        if (kb < 2) {
            *(float4*)(c1)     = *(const float4*)(row + 32 + kb * 8);
            *(float4*)(c1 + 4) = *(const float4*)(row + 32 + kb * 8 + 4);
        } else {
#pragma unroll
            for (int i = 0; i < 8; ++i) c1[i] = 0.0f;
        }
    }
    split8p(c0, ah0, al0);
    split8p(c1, ah1, al1);
    gemm3(ah0, al0, ah1, al1, rw1hi, rw1lo, lane, acc);

    float p[4] = {0.0f, 0.0f, 0.0f, 0.0f};
    {
        float bj[3], wj[3];
#pragma unroll
        for (int t = 0; t < 3; ++t) { bj[t] = rb1[t * 16 + m]; wj[t] = rw2[t * 16 + m]; }
#pragma unroll
        for (int t = 0; t < 3; ++t)
#pragma unroll
            for (int r = 0; r < 4; ++r)
                p[r] = fmaf(fmaxf(acc[t][r] + bj[t], 0.0f), wj[t], p[r]);
    }
#pragma unroll
    for (int o = 1; o < 16; o <<= 1) {
#pragma unroll
        for (int r = 0; r < 4; ++r) p[r] += __shfl_xor(p[r], o, 16);
    }
    if (m == 0) {
        float b2v = rb2[0];
#pragma unroll
        for (int r = 0; r < 4; ++r) {
            int n = n0 + kb * 4 + r;
            atomicAdd(out + gid[n], p[r] + b2v);
        }
    }
}

extern "C" void kernel_launch(void* const* d_in, const int* in_sizes, int n_in,
                              void* d_out, int out_size, void* d_ws, size_t ws_size,
                              hipStream_t stream) {
    const int*   AtomicNum = (const int*)  d_in[0];
    const int*   Edge      = (const int*)  d_in[1];
    const int*   graph_id  = (const int*)  d_in[2];
    const float* emb       = (const float*)d_in[3];
    const float* msg_w1    = (const float*)d_in[4];
    const float* msg_b1    = (const float*)d_in[5];
    const float* msg_w2    = (const float*)d_in[6];
    const float* msg_b2    = (const float*)d_in[7];
    const float* upd_w1    = (const float*)d_in[8];
    const float* upd_b1    = (const float*)d_in[9];
    const float* upd_w2    = (const float*)d_in[10];
    const float* upd_b2    = (const float*)d_in[11];
    const float* ro_w1     = (const float*)d_in[12];
    const float* ro_b1     = (const float*)d_in[13];
    const float* ro_w2     = (const float*)d_in[14];
    const float* ro_b2     = (const float*)d_in[15];

    const int N = in_sizes[0];          // 100000 (divisible by 16)
    const int E = in_sizes[1] / 2;      // 1600000
    const int* src = Edge;
    const int* dst = Edge + E;
    const int NB = (N + 255) >> NB_SH;  // 391 dst-buckets
    const int NBLK = (N + 1023) / 1024; // 98 scan blocks

    // workspace layout (~56 MB); h/h2 fp32 + hb/hb2 bf16 shadows, N+1 rows
    // each (row N = zero pad row). pairbuf aliases h2 (consumed pre layer 0).
    float*  h    = (float*)d_ws;                       // (N+1)*48 f32
    float*  h2   = h  + (size_t)(N + 1) * NE;          // (N+1)*48 f32
    int*    cnt  = (int*)(h2 + (size_t)(N + 1) * NE);  // N
    int*    offs = cnt + N;                            // N (end offsets after partB)
    int*    colsrc = offs + N;                         // E
    short8* whi  = (short8*)(colsrc + E);              // 3*2304 + 384
    short8* wlo  = whi + (3 * 2304 + 384);
    int*    gpos = (int*)(wlo + (3 * 2304 + 384));     // NB
    int*    bsum = gpos + NB;                          // NBLK
    float*  foldF = (float*)(bsum + NBLK);             // 6*48*48
    float*  b2u1  = foldF + 6 * NE * NE;               // 6*48
    unsigned short* hb  = (unsigned short*)(b2u1 + 6 * NE);   // (N+1)*48 bf16
    unsigned short* hb2 = hb + (size_t)(N + 1) * NE;          // (N+1)*48 bf16
    int2*   pairbuf = (int2*)h2;                       // E (aliases h2)

    hipMemsetAsync(d_out, 0, (size_t)out_size * sizeof(float), stream);
    hipMemsetAsync(cnt, 0, (size_t)N * sizeof(int), stream);
    hipMemsetAsync(h   + (size_t)N * NE, 0, NE * sizeof(float), stream);          // zero pad rows
    hipMemsetAsync(h2  + (size_t)N * NE, 0, NE * sizeof(float), stream);
    hipMemsetAsync(hb  + (size_t)N * NE, 0, NE * sizeof(unsigned short), stream);
    hipMemsetAsync(hb2 + (size_t)N * NE, 0, NE * sizeof(unsigned short), stream);

    int n4 = N * 12;
    embed_kernel<<<(n4 + 255) / 256, 256, 0, stream>>>(AtomicNum, emb, h, hb, n4);

    fold_kernel<<<(6 * NE * NE + 6 * NE + 255) / 256, 256, 0, stream>>>(
        msg_w2, upd_w1, msg_b2, foldF, b2u1);

    hist_kernel<<<(E + 255) / 256, 256, 0, stream>>>(dst, cnt, E);
    scansum_kernel<<<NBLK, 256, 0, stream>>>(cnt, bsum, N);
    scanb_kernel<<<1, 256, 0, stream>>>(bsum, NBLK);
    scanfix_kernel<<<NBLK, 1024, 0, stream>>>(cnt, bsum, offs, gpos, N);
    partA_kernel<<<(E + 2047) / 2048, 256, 0, stream>>>(src, dst, gpos, pairbuf, E, NB);
    partB_kernel<<<(E + 255) / 256, 256, 0, stream>>>(pairbuf, offs, colsrc, E);

    pack_all_kernel<<<(3 * 2304 + 384 + 255) / 256, 256, 0, stream>>>(
        msg_w1, foldF, upd_w2, ro_w1, whi, wlo);

    const float* hin = h;
    float* hout = h2;
    const unsigned short* hbin = hb;
    unsigned short* hbout = hb2;
    for (int l = 0; l < 6; ++l) {
        layer_kernel<<<N / 16, 64, 0, stream>>>(
            hin, hbin, colsrc, offs, cnt, hout, hbout,
            whi + 0 * 2304 + (size_t)l * 384,
            msg_b1 + (size_t)l * NE,
            whi + 1 * 2304 + (size_t)l * 384, wlo + 1 * 2304 + (size_t)l * 384,
            b2u1 + (size_t)l * NE,
            upd_b1 + (size_t)l * NE,
            whi + 2 * 2304 + (size_t)l * 384, wlo + 2 * 2304 + (size_t)l * 384,
            upd_b2 + (size_t)l * NE,
            N,
            (l == 5) ? 1 : 0,
            graph_id,
            whi + 3 * 2304, wlo + 3 * 2304,
            ro_b1, ro_w2, ro_b2, (float*)d_out);
        const float* tmpf = hin; hin = hout; hout = (float*)tmpf;
        const unsigned short* tmpb = hbin; hbin = hbout; hbout = (unsigned short*)tmpb;
    }
}

// Round 14
// 700.068 us; speedup vs baseline: 1.0919x; 1.0069x over previous
//
#include <hip/hip_runtime.h>
#include <hip/hip_bf16.h>

// VanillaMPNN on MI355X — round 32: 2-node gather-exposure batching on r28.
// r31 falsified footprint/line-count effects (FETCH -29%, time +11%): gather
// cost is fixed dependent-load latency per exposure. Only exposure-count cuts
// have ever paid (r28). r29/r30's pipeline failed on LDS residency, not
// mechanism -> batch in REGISTERS: pair adjacent nodes, issue both first-tile
// gathers back-to-back (one ~650cy exposure covers 2 nodes), compute A then B;
// overflow tiles (~5/wave) serial. +32 VGPR (~88 total, cap 20 waves/CU >>
// achieved 9), LDS unchanged 10.75KB. Numerics identical to r28.

#define NE 48
#define NB_SH 8                       // 256 nodes per bucket
#define SLDS_CAP 1024                 // staged edge indices per wave

typedef __attribute__((ext_vector_type(8))) short short8;
typedef __attribute__((ext_vector_type(4))) float floatx4;

__device__ __forceinline__ unsigned short bf16_rne(float v) {
    unsigned u = __float_as_uint(v);
    u += 0x7FFFu + ((u >> 16) & 1u);
    return (unsigned short)(u >> 16);
}

// packed hi/lo split: 8 fp32 -> 8 bf16 hi + 8 bf16 lo (RNE both)
__device__ __forceinline__ void split8p(const float* __restrict__ x, short8& hi, short8& lo) {
    union { unsigned u[4]; short8 s; } H, L;
#pragma unroll
    for (int i = 0; i < 4; ++i) {
        float a = x[2 * i], b = x[2 * i + 1];
        __hip_bfloat162 h2 = __float22bfloat162_rn(make_float2(a, b));
        unsigned h = *reinterpret_cast<unsigned*>(&h2);
        float ra = a - __uint_as_float(h << 16);
        float rb = b - __uint_as_float(h & 0xFFFF0000u);
        __hip_bfloat162 l2 = __float22bfloat162_rn(make_float2(ra, rb));
        H.u[i] = h;
        L.u[i] = *reinterpret_cast<unsigned*>(&l2);
    }
    hi = H.s; lo = L.s;
}

// plain pack: 8 fp32 -> 8 bf16 (RNE), no residual
__device__ __forceinline__ short8 cvt8(const float* __restrict__ x) {
    union { unsigned u[4]; short8 s; } H;
#pragma unroll
    for (int i = 0; i < 4; ++i) {
        __hip_bfloat162 h2 = __float22bfloat162_rn(make_float2(x[2 * i], x[2 * i + 1]));
        H.u[i] = *reinterpret_cast<unsigned*>(&h2);
    }
    return H.s;
}

// 3 j-tiles, 6 MFMA each: acc[t] = split3(A) @ B[t]
__device__ __forceinline__ void gemm3(const short8& ah0, const short8& al0,
                                      const short8& ah1, const short8& al1,
                                      const short8* __restrict__ hi,
                                      const short8* __restrict__ lo,
                                      int lane, floatx4* acc) {
#pragma unroll
    for (int t = 0; t < 3; ++t) {
        short8 bh0 = hi[(t * 2 + 0) * 64 + lane];
        short8 bh1 = hi[(t * 2 + 1) * 64 + lane];
        short8 bl0 = lo[(t * 2 + 0) * 64 + lane];
        short8 bl1 = lo[(t * 2 + 1) * 64 + lane];
        floatx4 c = {0.0f, 0.0f, 0.0f, 0.0f};
        c = __builtin_amdgcn_mfma_f32_16x16x32_bf16(ah0, bh0, c, 0, 0, 0);
        c = __builtin_amdgcn_mfma_f32_16x16x32_bf16(ah1, bh1, c, 0, 0, 0);
        c = __builtin_amdgcn_mfma_f32_16x16x32_bf16(al0, bh0, c, 0, 0, 0);
        c = __builtin_amdgcn_mfma_f32_16x16x32_bf16(al1, bh1, c, 0, 0, 0);
        c = __builtin_amdgcn_mfma_f32_16x16x32_bf16(ah0, bl0, c, 0, 0, 0);
        c = __builtin_amdgcn_mfma_f32_16x16x32_bf16(ah1, bl1, c, 0, 0, 0);
        acc[t] = c;
    }
}

// ---------------- embed ----------------
__global__ __launch_bounds__(256) void embed_kernel(const int* __restrict__ an,
                                                    const float* __restrict__ emb,
                                                    float* __restrict__ h, int n4) {
    int i = blockIdx.x * 256 + threadIdx.x;
    if (i >= n4) return;
    int n = i / 12, q = i - n * 12;
    ((float4*)h)[i] = ((const float4*)emb)[an[n] * 12 + q];
}

// ---------------- fold: F = msg_w2 @ upd_w1, b2u1 = msg_b2 @ upd_w1 ----------------
__global__ __launch_bounds__(256) void fold_kernel(const float* __restrict__ w2,
                                                   const float* __restrict__ u1,
                                                   const float* __restrict__ b2,
                                                   float* __restrict__ F,
                                                   float* __restrict__ b2u1) {
    int idx = blockIdx.x * 256 + threadIdx.x;
    if (idx < 6 * NE * NE) {
        int l = idx / (NE * NE);
        int r = idx - l * NE * NE;
        int k = r / NE, j = r - (r / NE) * NE;
        const float* wrow = w2 + (size_t)l * NE * NE + k * NE;
        const float* ucol = u1 + (size_t)l * NE * NE + j;
        float s = 0.0f;
#pragma unroll 8
        for (int q = 0; q < NE; ++q) s = fmaf(wrow[q], ucol[q * NE], s);
        F[idx] = s;
    } else if (idx < 6 * NE * NE + 6 * NE) {
        int r = idx - 6 * NE * NE;
        int l = r / NE, j = r - l * NE;
        const float* bv = b2 + (size_t)l * NE;
        const float* ucol = u1 + (size_t)l * NE * NE + j;
        float s = 0.0f;
#pragma unroll 8
        for (int q = 0; q < NE; ++q) s = fmaf(bv[q], ucol[q * NE], s);
        b2u1[r] = s;
    }
}

// ---------------- CSR build ----------------
__global__ __launch_bounds__(256) void hist_kernel(const int* __restrict__ dst,
                                                   int* __restrict__ cnt, int E) {
    int e = blockIdx.x * 256 + threadIdx.x;
    if (e < E) atomicAdd(&cnt[dst[e]], 1);
}

__global__ __launch_bounds__(256) void scansum_kernel(const int* __restrict__ cnt,
                                                      int* __restrict__ bsum, int N) {
    __shared__ int sw[4];
    const int tid = threadIdx.x, lane = tid & 63, wid = tid >> 6;
    int base = blockIdx.x * 1024;
    int v = 0;
#pragma unroll
    for (int k = 0; k < 4; ++k) {
        int i = base + k * 256 + tid;
        v += (i < N) ? cnt[i] : 0;
    }
#pragma unroll
    for (int o = 1; o < 64; o <<= 1) v += __shfl_xor(v, o, 64);
    if (lane == 0) sw[wid] = v;
    __syncthreads();
    if (tid == 0) bsum[blockIdx.x] = sw[0] + sw[1] + sw[2] + sw[3];
}

__global__ __launch_bounds__(256) void scanb_kernel(int* __restrict__ bsum, int nblk) {
    __shared__ int s[256];
    int tid = threadIdx.x;
    s[tid] = (tid < nblk) ? bsum[tid] : 0;
    __syncthreads();
    if (tid == 0) {
        int run = 0;
        for (int i = 0; i < nblk; ++i) { int t = s[i]; s[i] = run; run += t; }
    }
    __syncthreads();
    if (tid < nblk) bsum[tid] = s[tid];
}

__global__ __launch_bounds__(1024) void scanfix_kernel(const int* __restrict__ cnt,
                                                       const int* __restrict__ bsum,
                                                       int* __restrict__ offs,
                                                       int* __restrict__ gpos, int N) {
    __shared__ int swave[16];
    const int tid = threadIdx.x, lane = tid & 63, wid = tid >> 6;
    int i = blockIdx.x * 1024 + tid;
    int orig = (i < N) ? cnt[i] : 0;
    int v = orig;
#pragma unroll
    for (int off = 1; off < 64; off <<= 1) {
        int u = __shfl_up(v, off, 64);
        if (lane >= off) v += u;
    }
    if (lane == 63) swave[wid] = v;
    __syncthreads();
    if (wid == 0) {
        int w = (lane < 16) ? swave[lane] : 0;
#pragma unroll
        for (int off = 1; off < 16; off <<= 1) {
            int u = __shfl_up(w, off, 64);
            if (lane >= off) w += u;
        }
        if (lane < 16) swave[lane] = w;
    }
    __syncthreads();
    int prefix = (wid > 0) ? swave[wid - 1] : 0;
    int val = bsum[blockIdx.x] + prefix + v - orig;
    if (i < N) {
        offs[i] = val;
        if ((i & 255) == 0) gpos[i >> 8] = val;
    }
}

__global__ __launch_bounds__(256) void partA_kernel(const int* __restrict__ src,
                                                    const int* __restrict__ dst,
                                                    int* __restrict__ gpos,
                                                    int2* __restrict__ pairbuf,
                                                    int E, int NB) {
    __shared__ int lhist[512];
    __shared__ int lbase[512];
    const int tid = threadIdx.x;
    for (int i = tid; i < NB; i += 256) lhist[i] = 0;
    __syncthreads();
    const int base = blockIdx.x * 2048;
    int ssrc[8], sdst[8], rnk[8];
#pragma unroll
    for (int k = 0; k < 8; ++k) {
        int e = base + k * 256 + tid;
        if (e < E) {
            ssrc[k] = src[e]; sdst[k] = dst[e];
            rnk[k] = atomicAdd(&lhist[sdst[k] >> NB_SH], 1);
        }
    }
    __syncthreads();
    for (int i = tid; i < NB; i += 256) {
        int c = lhist[i];
        lbase[i] = c ? atomicAdd(&gpos[i], c) : 0;
    }
    __syncthreads();
#pragma unroll
    for (int k = 0; k < 8; ++k) {
        int e = base + k * 256 + tid;
        if (e < E)
            pairbuf[lbase[sdst[k] >> NB_SH] + rnk[k]] = make_int2(ssrc[k], sdst[k]);
    }
}

__global__ __launch_bounds__(256) void partB_kernel(const int2* __restrict__ pairbuf,
                                                    int* __restrict__ offs,   // becomes END offsets
                                                    int* __restrict__ colsrc, int E) {
    int e = blockIdx.x * 256 + threadIdx.x;
    if (e < E) {
        int2 p = pairbuf[e];
        int pos = atomicAdd(&offs[p.y], 1);
        colsrc[pos] = p.x;
    }
}

// ---------------- pack 4 weight families -> B-fragment tables ----------------
__global__ __launch_bounds__(256) void pack_all_kernel(const float* __restrict__ w0,
                                                       const float* __restrict__ w1m,
                                                       const float* __restrict__ w2m,
                                                       const float* __restrict__ w3m,
                                                       short8* __restrict__ hi,
                                                       short8* __restrict__ lo) {
    int idx = blockIdx.x * 256 + threadIdx.x;
    if (idx >= 3 * 2304 + 384) return;
    int slot = idx / 2304;
    int rem  = idx - slot * 2304;
    const float* w = (slot == 0) ? w0 : (slot == 1) ? w1m : (slot == 2) ? w2m : w3m;
    int lane = rem & 63;
    int s = (rem >> 6) & 1;
    int t = (rem >> 7) % 3;
    int l = (rem >> 7) / 3;
    short8 h8, l8;
#pragma unroll
    for (int i = 0; i < 8; ++i) {
        int k = s * 32 + (lane >> 4) * 8 + i;
        int j = t * 16 + (lane & 15);
        float v = (k < NE) ? w[l * NE * NE + k * NE + j] : 0.0f;
        unsigned short hh = bf16_rne(v);
        float hf = __uint_as_float((unsigned)hh << 16);
        unsigned short ll = bf16_rne(v - hf);
        h8[i] = (short)hh;
        l8[i] = (short)ll;
    }
    hi[idx] = h8;
    lo[idx] = l8;
}

// ---------------- fused layer: 2-node-batched edge agg + folded node transform ----------------
__global__ __launch_bounds__(64, 4) void layer_kernel(
    const float* __restrict__ hin,
    const int* __restrict__ colsrc,
    const int* __restrict__ ends,
    const int* __restrict__ cnt,
    float* __restrict__ hout,
    const short8* __restrict__ bhi,               // msg_w1 frags [3][2][64]
    const float* __restrict__ b1,                 // msg_b1
    const short8* __restrict__ f1hi, const short8* __restrict__ f1lo,   // F = W2*U1
    const float* __restrict__ b2u1v,
    const float* __restrict__ ub1,
    const short8* __restrict__ u2hi, const short8* __restrict__ u2lo,   // upd_w2
    const float* __restrict__ ub2,
    int N,
    int final_layer,
    const int* __restrict__ gid,
    const short8* __restrict__ rw1hi, const short8* __restrict__ rw1lo,
    const float* __restrict__ rb1, const float* __restrict__ rw2,
    const float* __restrict__ rb2, float* __restrict__ out)
{
    __shared__ float mytile[16][52];              // 16x48 agg tile (+pad)
    __shared__ float hdls[16][48];                // staged dst rows
    __shared__ int   slds[SLDS_CAP];              // staged edge indices
    const int lane = threadIdx.x;
    const int n0   = blockIdx.x * 16;
    if (n0 >= N) return;

    const int m  = lane & 15;
    const int kb = lane >> 4;

    // ---- coop-stage 16 dst rows into LDS (one latency exposure) ----
    {
        const float4* sp = (const float4*)(hin + (size_t)n0 * NE);
        float4* dp = (float4*)hdls;
#pragma unroll
        for (int f = 0; f < 3; ++f) dp[lane + f * 64] = sp[lane + f * 64];
    }

    // ---- per-node metadata in registers (lane m holds node m's values) ----
    const int mydeg = cnt[n0 + m];
    const int myend = ends[n0 + m];

    // ---- coop-stage the wave's contiguous edge-index range ----
    const int beg0 = __shfl(myend - mydeg, 0, 64);
    const int endL = __shfl(myend, 15, 64);
    const int tot  = endL - beg0;
    const bool uselds = (tot <= SLDS_CAP);
    if (uselds) {
        for (int i = lane; i < tot; i += 64) slds[i] = colsrc[beg0 + i];
    }

    // ---- edge weight fragments in registers (bf16 hi only) ----
    short8 bh[6];
#pragma unroll
    for (int i = 0; i < 6; ++i) bh[i] = bhi[i * 64 + lane];
    const float bb0 = b1[m], bb1 = b1[16 + m], bb2 = b1[32 + m];
    const float rbb0 = fmaxf(bb0, 0.0f), rbb1 = fmaxf(bb1, 0.0f), rbb2 = fmaxf(bb2, 0.0f);
    const float rbb_mine = (lane < 16) ? rbb0 : (lane < 32) ? rbb1 : rbb2;

    asm volatile("s_waitcnt vmcnt(0) lgkmcnt(0)" ::: "memory");  // stages complete

    // ---------------- edge phase: 2-node-batched aggregation (bf16) ----------------
    float s0 = 0.0f, s1 = 0.0f, s2 = 0.0f;
    float4 d0a = make_float4(0, 0, 0, 0), d0b = d0a, d1a = d0a, d1b = d0a;

    auto getidx = [&](int e) -> int {
        return uselds ? slds[e - beg0] : colsrc[e];
    };
    auto load_drow = [&](int nn) {
        const float* hr = hdls[nn];
        d0a = *(const float4*)(hr + kb * 8);
        d0b = *(const float4*)(hr + kb * 8 + 4);
        if (kb < 2) {
            d1a = *(const float4*)(hr + 32 + kb * 8);
            d1b = *(const float4*)(hr + 32 + kb * 8 + 4);
        }
    };
    auto compute_tile = [&](const float4& a0, const float4& a1,
                            const float4& a2, const float4& a3) {
        float x0[8], x1[8];
        x0[0] = a0.x * d0a.x; x0[1] = a0.y * d0a.y; x0[2] = a0.z * d0a.z; x0[3] = a0.w * d0a.w;
        x0[4] = a1.x * d0b.x; x0[5] = a1.y * d0b.y; x0[6] = a1.z * d0b.z; x0[7] = a1.w * d0b.w;
        if (kb < 2) {
            x1[0] = a2.x * d1a.x; x1[1] = a2.y * d1a.y; x1[2] = a2.z * d1a.z; x1[3] = a2.w * d1a.w;
            x1[4] = a3.x * d1b.x; x1[5] = a3.y * d1b.y; x1[6] = a3.z * d1b.z; x1[7] = a3.w * d1b.w;
        } else {
#pragma unroll
            for (int i = 0; i < 8; ++i) x1[i] = 0.0f;
        }
        short8 ah0 = cvt8(x0);
        short8 ah1 = cvt8(x1);
#pragma unroll
        for (int tt = 0; tt < 3; ++tt) {
            floatx4 cc = {0.0f, 0.0f, 0.0f, 0.0f};
            cc = __builtin_amdgcn_mfma_f32_16x16x32_bf16(ah0, bh[tt * 2 + 0], cc, 0, 0, 0);
            cc = __builtin_amdgcn_mfma_f32_16x16x32_bf16(ah1, bh[tt * 2 + 1], cc, 0, 0, 0);
            const float bb = (tt == 0) ? bb0 : (tt == 1) ? bb1 : bb2;
            float ts = 0.0f;
#pragma unroll
            for (int r = 0; r < 4; ++r)
                ts += fmaxf(cc[r] + bb, 0.0f);        // pad rows contribute relu(bb)
            if (tt == 0) s0 += ts; else if (tt == 1) s1 += ts; else s2 += ts;
        }
    };
    auto finalize = [&](int nn, int deg) {
        s0 += __shfl_xor(s0, 16, 64); s0 += __shfl_xor(s0, 32, 64);
        s1 += __shfl_xor(s1, 16, 64); s1 += __shfl_xor(s1, 32, 64);
        s2 += __shfl_xor(s2, 16, 64); s2 += __shfl_xor(s2, 32, 64);
        float t1v = __shfl(s1, lane & 15, 64);
        float t2v = __shfl(s2, lane & 15, 64);
        float val = (lane < 16) ? s0 : (lane < 32) ? t1v : t2v;
        const float npad = (float)((((deg + 15) >> 4) << 4) - deg);
        val = fmaf(-npad, rbb_mine, val);
        if (lane < 48) mytile[nn][lane] = val;
    };
    auto tail_tiles = [&](int deg, int beg) {            // tiles 1..ntile-1 (rare)
        const int ntile = (deg + 15) >> 4;
        for (int it = 1; it < ntile; ++it) {
            const int rem = deg - it * 16;
            int srow = (m < rem) ? getidx(beg + it * 16 + m) : N;
            const float* hs = hin + (size_t)srow * NE + kb * 8;
            float4 a0 = ((const float4*)hs)[0];
            float4 a1 = ((const float4*)hs)[1];
            float4 a2 = make_float4(0, 0, 0, 0), a3 = a2;
            if (kb < 2) {
                a2 = ((const float4*)(hs + 32))[0];
                a3 = ((const float4*)(hs + 32))[1];
            }
            compute_tile(a0, a1, a2, a3);
        }
    };

#pragma unroll 1
    for (int np = 0; np < 16; np += 2) {
        const int degA = __shfl(mydeg, np, 64);
        const int endA = __shfl(myend, np, 64);
        const int degB = __shfl(mydeg, np + 1, 64);
        const int endB = __shfl(myend, np + 1, 64);
        const int begA = endA - degA, begB = endB - degB;

        // issue BOTH first-tile gathers back-to-back: one exposure, two nodes
        int srowA = (m < degA) ? getidx(begA + m) : N;
        int srowB = (m < degB) ? getidx(begB + m) : N;
        const float* hsA = hin + (size_t)srowA * NE + kb * 8;
        const float* hsB = hin + (size_t)srowB * NE + kb * 8;
        float4 A0 = ((const float4*)hsA)[0];
        float4 A1 = ((const float4*)hsA)[1];
        float4 A2 = make_float4(0, 0, 0, 0), A3 = A2, B2 = A2, B3 = A2;
        if (kb < 2) {
            A2 = ((const float4*)(hsA + 32))[0];
            A3 = ((const float4*)(hsA + 32))[1];
        }
        float4 B0 = ((const float4*)hsB)[0];
        float4 B1 = ((const float4*)hsB)[1];
        if (kb < 2) {
            B2 = ((const float4*)(hsB + 32))[0];
            B3 = ((const float4*)(hsB + 32))[1];
        }

        // node A
        load_drow(np);
        s0 = s1 = s2 = 0.0f;
        if (degA > 0) {
            compute_tile(A0, A1, A2, A3);
            tail_tiles(degA, begA);
        }
        finalize(np, degA);

        // node B
        load_drow(np + 1);
        s0 = s1 = s2 = 0.0f;
        if (degB > 0) {
            compute_tile(B0, B1, B2, B3);
            tail_tiles(degB, begB);
        }
        finalize(np + 1, degB);
    }
    asm volatile("s_waitcnt lgkmcnt(0)" ::: "memory");

    // ---------------- node phase: 2 GEMMs (folded, full hi/lo) + fused readout ----------------
    float c0[8], c1[8];
    {
        const float* row = &mytile[m][0];
        *(float4*)(c0)     = *(const float4*)(row + kb * 8);
        *(float4*)(c0 + 4) = *(const float4*)(row + kb * 8 + 4);
        if (kb < 2) {
            *(float4*)(c1)     = *(const float4*)(row + 32 + kb * 8);
            *(float4*)(c1 + 4) = *(const float4*)(row + 32 + kb * 8 + 4);
        } else {
#pragma unroll
            for (int i = 0; i < 8; ++i) c1[i] = 0.0f;
        }
    }
    asm volatile("s_waitcnt lgkmcnt(0)" ::: "memory");
    short8 ah0, al0, ah1, al1;
    split8p(c0, ah0, al0);
    split8p(c1, ah1, al1);

    floatx4 acc[3];
    gemm3(ah0, al0, ah1, al1, f1hi, f1lo, lane, acc);   // agg @ F
    {
        float dj[3], bj[3];
#pragma unroll
        for (int t = 0; t < 3; ++t) { dj[t] = b2u1v[t * 16 + m]; bj[t] = ub1[t * 16 + m]; }
#pragma unroll
        for (int r = 0; r < 4; ++r) {
            float fd = (float)__shfl(mydeg, kb * 4 + r, 64);
#pragma unroll
            for (int t = 0; t < 3; ++t)
                acc[t][r] = fmaxf(fmaf(fd, dj[t], acc[t][r]) + bj[t], 0.0f);
        }
    }

    // transpose C->A, GEMM2: T @ U2
#pragma unroll
    for (int t = 0; t < 3; ++t)
#pragma unroll
        for (int r = 0; r < 4; ++r)
            mytile[kb * 4 + r][t * 16 + m] = acc[t][r];
    asm volatile("s_waitcnt lgkmcnt(0)" ::: "memory");
    {
        const float* row = &mytile[m][0];
        *(float4*)(c0)     = *(const float4*)(row + kb * 8);
        *(float4*)(c0 + 4) = *(const float4*)(row + kb * 8 + 4);
        if (kb < 2) {
            *(float4*)(c1)     = *(const float4*)(row + 32 + kb * 8);
            *(float4*)(c1 + 4) = *(const float4*)(row + 32 + kb * 8 + 4);
        } else {
#pragma unroll
            for (int i = 0; i < 8; ++i) c1[i] = 0.0f;
        }
    }
    asm volatile("s_waitcnt lgkmcnt(0)" ::: "memory");
    split8p(c0, ah0, al0);
    split8p(c1, ah1, al1);
    gemm3(ah0, al0, ah1, al1, u2hi, u2lo, lane, acc);

    // out_h = hin + ub2 + acc  (residual from staged hdls)
    {
        float bj[3];
#pragma unroll
        for (int t = 0; t < 3; ++t) bj[t] = ub2[t * 16 + m];
#pragma unroll
        for (int r = 0; r < 4; ++r) {
#pragma unroll
            for (int t = 0; t < 3; ++t)
                acc[t][r] += hdls[kb * 4 + r][t * 16 + m] + bj[t];
        }
    }

    if (!final_layer) {
#pragma unroll
        for (int r = 0; r < 4; ++r) {
            const size_t row = (size_t)(n0 + kb * 4 + r) * NE;
#pragma unroll
            for (int t = 0; t < 3; ++t)
                hout[row + t * 16 + m] = acc[t][r];
        }
        return;
    }

    // fused readout: y = relu(h @ ro_w1 + rb1) . rw2 + rb2 ; segment-sum by gid
#pragma unroll
    for (int t = 0; t < 3; ++t)
#pragma unroll
        for (int r = 0; r < 4; ++r)
            mytile[kb * 4 + r][t * 16 + m] = acc[t][r];
    asm volatile("s_waitcnt lgkmcnt(0)" ::: "memory");
    {
        const float* row = &mytile[m][0];
        *(float4*)(c0)     = *(const float4*)(row + kb * 8);
        *(float4*)(c0 + 4) = *(const float4*)(row + kb * 8 + 4);
        if (kb < 2) {
            *(float4*)(c1)     = *(const float4*)(row + 32 + kb * 8);
            *(float4*)(c1 + 4) = *(const float4*)(row + 32 + kb * 8 + 4);
        } else {
#pragma unroll
            for (int i = 0; i < 8; ++i) c1[i] = 0.0f;
        }
    }
    split8p(c0, ah0, al0);
    split8p(c1, ah1, al1);
    gemm3(ah0, al0, ah1, al1, rw1hi, rw1lo, lane, acc);

    float p[4] = {0.0f, 0.0f, 0.0f, 0.0f};
    {
        float bj[3], wj[3];
#pragma unroll
        for (int t = 0; t < 3; ++t) { bj[t] = rb1[t * 16 + m]; wj[t] = rw2[t * 16 + m]; }
#pragma unroll
        for (int t = 0; t < 3; ++t)
#pragma unroll
            for (int r = 0; r < 4; ++r)
                p[r] = fmaf(fmaxf(acc[t][r] + bj[t], 0.0f), wj[t], p[r]);
    }
#pragma unroll
    for (int o = 1; o < 16; o <<= 1) {
#pragma unroll
        for (int r = 0; r < 4; ++r) p[r] += __shfl_xor(p[r], o, 16);
    }
    if (m == 0) {
        float b2v = rb2[0];
#pragma unroll
        for (int r = 0; r < 4; ++r) {
            int n = n0 + kb * 4 + r;
            atomicAdd(out + gid[n], p[r] + b2v);
        }
    }
}

extern "C" void kernel_launch(void* const* d_in, const int* in_sizes, int n_in,
                              void* d_out, int out_size, void* d_ws, size_t ws_size,
                              hipStream_t stream) {
    const int*   AtomicNum = (const int*)  d_in[0];
    const int*   Edge      = (const int*)  d_in[1];
    const int*   graph_id  = (const int*)  d_in[2];
    const float* emb       = (const float*)d_in[3];
    const float* msg_w1    = (const float*)d_in[4];
    const float* msg_b1    = (const float*)d_in[5];
    const float* msg_w2    = (const float*)d_in[6];
    const float* msg_b2    = (const float*)d_in[7];
    const float* upd_w1    = (const float*)d_in[8];
    const float* upd_b1    = (const float*)d_in[9];
    const float* upd_w2    = (const float*)d_in[10];
    const float* upd_b2    = (const float*)d_in[11];
    const float* ro_w1     = (const float*)d_in[12];
    const float* ro_b1     = (const float*)d_in[13];
    const float* ro_w2     = (const float*)d_in[14];
    const float* ro_b2     = (const float*)d_in[15];

    const int N = in_sizes[0];          // 100000 (divisible by 16)
    const int E = in_sizes[1] / 2;      // 1600000
    const int* src = Edge;
    const int* dst = Edge + E;
    const int NB = (N + 255) >> NB_SH;  // 391 dst-buckets
    const int NBLK = (N + 1023) / 1024; // 98 scan blocks

    // workspace layout (~46 MB); h/h2 have N+1 rows (row N = zero pad row).
    float*  h    = (float*)d_ws;                       // (N+1)*48
    float*  h2   = h  + (size_t)(N + 1) * NE;          // (N+1)*48
    int*    cnt  = (int*)(h2 + (size_t)(N + 1) * NE);  // N
    int*    offs = cnt + N;                            // N (end offsets after partB)
    int*    colsrc = offs + N;                         // E
    short8* whi  = (short8*)(colsrc + E);              // 3*2304 + 384
    short8* wlo  = whi + (3 * 2304 + 384);
    int*    gpos = (int*)(wlo + (3 * 2304 + 384));     // NB
    int*    bsum = gpos + NB;                          // NBLK
    float*  foldF = (float*)(bsum + NBLK);             // 6*48*48
    float*  b2u1  = foldF + 6 * NE * NE;               // 6*48
    int2*   pairbuf = (int2*)h2;                       // E (aliases h2)

    hipMemsetAsync(d_out, 0, (size_t)out_size * sizeof(float), stream);
    hipMemsetAsync(cnt, 0, (size_t)N * sizeof(int), stream);
    hipMemsetAsync(h  + (size_t)N * NE, 0, NE * sizeof(float), stream);  // zero pad row
    hipMemsetAsync(h2 + (size_t)N * NE, 0, NE * sizeof(float), stream);  // zero pad row

    int n4 = N * 12;
    embed_kernel<<<(n4 + 255) / 256, 256, 0, stream>>>(AtomicNum, emb, h, n4);

    fold_kernel<<<(6 * NE * NE + 6 * NE + 255) / 256, 256, 0, stream>>>(
        msg_w2, upd_w1, msg_b2, foldF, b2u1);

    hist_kernel<<<(E + 255) / 256, 256, 0, stream>>>(dst, cnt, E);
    scansum_kernel<<<NBLK, 256, 0, stream>>>(cnt, bsum, N);
    scanb_kernel<<<1, 256, 0, stream>>>(bsum, NBLK);
    scanfix_kernel<<<NBLK, 1024, 0, stream>>>(cnt, bsum, offs, gpos, N);
    partA_kernel<<<(E + 2047) / 2048, 256, 0, stream>>>(src, dst, gpos, pairbuf, E, NB);
    partB_kernel<<<(E + 255) / 256, 256, 0, stream>>>(pairbuf, offs, colsrc, E);

    pack_all_kernel<<<(3 * 2304 + 384 + 255) / 256, 256, 0, stream>>>(
        msg_w1, foldF, upd_w2, ro_w1, whi, wlo);

    const float* hin = h;
    float* hout = h2;
    for (int l = 0; l < 6; ++l) {
        layer_kernel<<<N / 16, 64, 0, stream>>>(
            hin, colsrc, offs, cnt, hout,
            whi + 0 * 2304 + (size_t)l * 384,
            msg_b1 + (size_t)l * NE,
            whi + 1 * 2304 + (size_t)l * 384, wlo + 1 * 2304 + (size_t)l * 384,
            b2u1 + (size_t)l * NE,
            upd_b1 + (size_t)l * NE,
            whi + 2 * 2304 + (size_t)l * 384, wlo + 2 * 2304 + (size_t)l * 384,
            upd_b2 + (size_t)l * NE,
            N,
            (l == 5) ? 1 : 0,
            graph_id,
            whi + 3 * 2304, wlo + 3 * 2304,
            ro_b1, ro_w2, ro_b2, (float*)d_out);
        const float* tmp = hin; hin = hout; hout = (float*)tmp;
    }
}